// Round 11
// baseline (445.237 us; speedup 1.0000x reference)
//
#include <hip/hip_runtime.h>
#include <math.h>

#define NB 8
#define IC 256
#define CC 64
#define HH 128
#define WW 128
#define NN (HH*WW)      // 16384
#define NKW 64
#define NKC 64

typedef _Float16 f16x8 __attribute__((ext_vector_type(8)));
typedef float f32x4 __attribute__((ext_vector_type(4)));

// ---------------- workspace layout (floats) ----------------
static constexpr size_t SZ_INP  = (size_t)NB * CC * NN;            // 8,388,608
static constexpr size_t OFF_INP = 0;
static constexpr size_t OFF_S   = OFF_INP + SZ_INP;                // s AND pW (aliased)
static constexpr size_t OFF_PC  = OFF_S + SZ_INP;                  // pC: NB*NKC*4096
static constexpr size_t OFF_TW  = OFF_PC + (size_t)NB * NKC * 4096;
static constexpr size_t OFF_TC  = OFF_TW + (size_t)NB * 16384;
static constexpr size_t OFF_WT  = OFF_TC + (size_t)NB * 4096;      // w_in fp16 [64 o][256 i]
static constexpr size_t OFF_WOT = OFF_WT + 16384;                  // w_out fp16 [256 o][64 c]

// ---------------- weight fp16 casts (layouts already k-contiguous for MFMA A-frags) ----------------
__global__ __launch_bounds__(256) void k_wt(
    const float* __restrict__ w_in, const float* __restrict__ w_out,
    _Float16* __restrict__ wh, _Float16* __restrict__ woh)
{
    const int idx = blockIdx.x * 256 + threadIdx.x;   // 0..32767
    if (idx < 16384) wh[idx] = (_Float16)w_in[idx];           // [o][i]
    else             woh[idx - 16384] = (_Float16)w_out[idx - 16384];  // [o][c]
}

// ---------------- inconv via MFMA fp16: inp[b,o,n] = sum_i w[o,i]*x[b,i,n] + b_in[o] ----------------
// LEDGER: every fp32 schedule = 80us (~40% VALU wall, rounds 0-10). MFMA fp16 @2PF makes
// this HBM-bound: 134MB x-read + 34MB inp-write -> ~27us floor. fp32 accumulate; fp16
// input error ~1e-3 absolute, small vs reported absmax 0.0156.
// Frag maps (guide §3): A row=l&15,k=(l>>4)*8+j; B col=l&15,k same; D col=l&15,row=(l>>4)*4+r.
// grid (NN/128, NB), block 256 (4 waves). Tile 64o x 128n, K=256 in 8 chunks of 32.
// W (64x256 fp16, 33KB) in LDS once; x-chunk cvt'd to fp16 [i][136] per chunk.
__global__ __launch_bounds__(256) void k_inconv(
    const float* __restrict__ x, const _Float16* __restrict__ wh,
    const float* __restrict__ b_in, float* __restrict__ inp)
{
    __shared__ _Float16 wl[64 * 264];   // [o][i], stride 264 (16B-aligned rows, bank-spread)
    __shared__ _Float16 xh[32 * 136];   // [i][n], stride 136
    const int b  = blockIdx.y;
    const int n0 = blockIdx.x * 128;
    const int t  = threadIdx.x;
    const int l  = t & 63, wv = t >> 6;
    const int lr = l & 15, kg = (l >> 4) * 8;

    {   // load W once: 64 rows x 256 halves
        const int r = t >> 2, c = (t & 3) * 64;
        const uint4* src = (const uint4*)(wh + r * 256 + c);
        uint4* dst = (uint4*)(wl + r * 264 + c);
#pragma unroll
        for (int k = 0; k < 8; k++) dst[k] = src[k];
    }

    f32x4 acc[4][2];
#pragma unroll
    for (int mt = 0; mt < 4; mt++)
#pragma unroll
        for (int nt = 0; nt < 2; nt++) acc[mt][nt] = (f32x4){0.f, 0.f, 0.f, 0.f};

    for (int kc = 0; kc < 8; ++kc) {
        __syncthreads();
        {   // stage x chunk: 32 i x 128 n fp32 -> fp16, vectorized
            const int i = t >> 3, nq = (t & 7) * 16;
            const float* src = x + ((size_t)b * IC + kc * 32 + i) * NN + n0 + nq;
            const float4 v0 = *(const float4*)(src);
            const float4 v1 = *(const float4*)(src + 4);
            const float4 v2 = *(const float4*)(src + 8);
            const float4 v3 = *(const float4*)(src + 12);
            f16x8 h0, h1;
            h0[0] = (_Float16)v0.x; h0[1] = (_Float16)v0.y;
            h0[2] = (_Float16)v0.z; h0[3] = (_Float16)v0.w;
            h0[4] = (_Float16)v1.x; h0[5] = (_Float16)v1.y;
            h0[6] = (_Float16)v1.z; h0[7] = (_Float16)v1.w;
            h1[0] = (_Float16)v2.x; h1[1] = (_Float16)v2.y;
            h1[2] = (_Float16)v2.z; h1[3] = (_Float16)v2.w;
            h1[4] = (_Float16)v3.x; h1[5] = (_Float16)v3.y;
            h1[6] = (_Float16)v3.z; h1[7] = (_Float16)v3.w;
            *(f16x8*)(xh + i * 136 + nq)     = h0;
            *(f16x8*)(xh + i * 136 + nq + 8) = h1;
        }
        __syncthreads();

        f16x8 bf[2];
#pragma unroll
        for (int nt = 0; nt < 2; ++nt) {
            const int n = wv * 32 + nt * 16 + lr;
#pragma unroll
            for (int j = 0; j < 8; ++j) bf[nt][j] = xh[(kg + j) * 136 + n];
        }
#pragma unroll
        for (int mt = 0; mt < 4; ++mt) {
            const f16x8 af = *(const f16x8*)(wl + (mt * 16 + lr) * 264 + kc * 32 + kg);
            acc[mt][0] = __builtin_amdgcn_mfma_f32_16x16x32_f16(af, bf[0], acc[mt][0], 0, 0, 0);
            acc[mt][1] = __builtin_amdgcn_mfma_f32_16x16x32_f16(af, bf[1], acc[mt][1], 0, 0, 0);
        }
    }

#pragma unroll
    for (int mt = 0; mt < 4; ++mt)
#pragma unroll
        for (int nt = 0; nt < 2; ++nt) {
            const int n = n0 + wv * 32 + nt * 16 + lr;
#pragma unroll
            for (int r = 0; r < 4; ++r) {
                const int o = mt * 16 + (l >> 4) * 4 + r;
                inp[((size_t)b * CC + o) * NN + n] = (float)acc[mt][nt][r] + b_in[o];
            }
        }
}

// ---------------- gram W partials: K-chunk 32, vectorized padded staging ----------------
__global__ __launch_bounds__(256) void k_gramW(const float* __restrict__ inp, float* __restrict__ pW)
{
    __shared__ float xs[32 * 132];
    const int b = blockIdx.y, kc = blockIdx.x;
    const int t = threadIdx.x, tx = t & 15, ty = t >> 4;
    const float* Xb = inp + (size_t)b * CC * NN;
    const int k0 = kc * ((CC * HH) / NKW);

    float acc[8][8];
#pragma unroll
    for (int i = 0; i < 8; i++)
#pragma unroll
        for (int j = 0; j < 8; j++) acc[i][j] = 0.f;

    for (int kk = k0; kk < k0 + (CC * HH) / NKW; kk += 32) {
        __syncthreads();
        {
            const int r = t >> 3, cq = (t & 7) * 16;
            const float* src = Xb + ((size_t)kk + r) * WW + cq;
            float* dst = xs + r * 132 + cq;
#pragma unroll
            for (int j = 0; j < 4; j++)
                *(float4*)(dst + 4 * j) = *(const float4*)(src + 4 * j);
        }
        __syncthreads();
#pragma unroll 8
        for (int k = 0; k < 32; k++) {
            const float* row = xs + k * 132;
            float4 t0 = *(const float4*)(row + ty * 8);
            float4 t1 = *(const float4*)(row + ty * 8 + 4);
            float4 u0 = *(const float4*)(row + tx * 8);
            float4 u1 = *(const float4*)(row + tx * 8 + 4);
            float av[8] = {t0.x, t0.y, t0.z, t0.w, t1.x, t1.y, t1.z, t1.w};
            float bv[8] = {u0.x, u0.y, u0.z, u0.w, u1.x, u1.y, u1.z, u1.w};
#pragma unroll
            for (int i = 0; i < 8; i++)
#pragma unroll
                for (int j = 0; j < 8; j++) acc[i][j] += av[i] * bv[j];
        }
    }
    float* dst = pW + ((size_t)b * NKW + kc) * 16384;
#pragma unroll
    for (int i = 0; i < 8; i++)
#pragma unroll
        for (int j = 0; j < 8; j += 4) {
            float4 v = make_float4(acc[i][j], acc[i][j + 1], acc[i][j + 2], acc[i][j + 3]);
            *(float4*)(dst + (ty * 8 + i) * 128 + tx * 8 + j) = v;
        }
}

__global__ __launch_bounds__(256) void k_redW(const float* __restrict__ pW, float* __restrict__ Tw)
{
    const int b = blockIdx.y;
    const int idx = blockIdx.x * 256 + threadIdx.x;
    const float* p = pW + (size_t)b * NKW * 16384 + idx;
    float acc = 0.f;
#pragma unroll
    for (int k = 0; k < NKW; k++) acc += p[(size_t)k * 16384];
    Tw[(size_t)b * 16384 + idx] = acc;
}

__global__ __launch_bounds__(1024) void k_softW(float* __restrict__ Tw)
{
    __shared__ float red[32 * 33];
    const int b = blockIdx.x, v0 = blockIdx.y * 32;
    const int t = threadIdx.x;
    const int vc = t & 31, wg = t >> 5;
    float* S = Tw + (size_t)b * 16384 + v0 + vc;

    float v[4];
    float m = -3.4e38f;
#pragma unroll
    for (int j = 0; j < 4; j++) { v[j] = S[(wg * 4 + j) * 128]; m = fmaxf(m, v[j]); }
    red[wg * 33 + vc] = m;
    __syncthreads();
    for (int st = 16; st > 0; st >>= 1) {
        if (wg < st) red[wg * 33 + vc] = fmaxf(red[wg * 33 + vc], red[(wg + st) * 33 + vc]);
        __syncthreads();
    }
    m = red[vc];
    __syncthreads();
    float sum = 0.f;
#pragma unroll
    for (int j = 0; j < 4; j++) { v[j] = __expf(v[j] - m); sum += v[j]; }
    red[wg * 33 + vc] = sum;
    __syncthreads();
    for (int st = 16; st > 0; st >>= 1) {
        if (wg < st) red[wg * 33 + vc] += red[(wg + st) * 33 + vc];
        __syncthreads();
    }
    const float inv = 1.f / red[vc];
#pragma unroll
    for (int j = 0; j < 4; j++) S[(wg * 4 + j) * 128] = v[j] * inv;
}

// ---------------- gram C partials: transposed LDS tile [n][c] ----------------
__global__ __launch_bounds__(256) void k_gramC(const float* __restrict__ inp, float* __restrict__ pC)
{
    __shared__ float xt[32 * 68];
    const int b = blockIdx.y, nc = blockIdx.x;
    const int t = threadIdx.x, tx = t & 15, ty = t >> 4;
    const float* ip = inp + (size_t)b * CC * NN;
    const int n0 = nc * (NN / NKC);

    float acc[4][4];
#pragma unroll
    for (int i = 0; i < 4; i++)
#pragma unroll
        for (int j = 0; j < 4; j++) acc[i][j] = 0.f;

    const int scc = t >> 2;
    const int sn  = (t & 3) * 8;

    for (int nt = 0; nt < NN / NKC; nt += 32) {
        __syncthreads();
        {
            const float* src = ip + (size_t)scc * NN + n0 + nt + sn;
            float v[8];
            *(float4*)(v)     = *(const float4*)(src);
            *(float4*)(v + 4) = *(const float4*)(src + 4);
#pragma unroll
            for (int j = 0; j < 8; j++) xt[(sn + j) * 68 + scc] = v[j];
        }
        __syncthreads();
#pragma unroll 8
        for (int nn = 0; nn < 32; nn++) {
            const float4 a4 = *(const float4*)(xt + nn * 68 + ty * 4);
            const float4 e4 = *(const float4*)(xt + nn * 68 + tx * 4);
            const float av[4] = {a4.x, a4.y, a4.z, a4.w};
            const float ev[4] = {e4.x, e4.y, e4.z, e4.w};
#pragma unroll
            for (int i = 0; i < 4; i++)
#pragma unroll
                for (int j = 0; j < 4; j++) acc[i][j] += av[i] * ev[j];
        }
    }
    float* dst = pC + ((size_t)b * NKC + nc) * 4096;
#pragma unroll
    for (int i = 0; i < 4; i++) {
        float4 v = make_float4(acc[i][0], acc[i][1], acc[i][2], acc[i][3]);
        *(float4*)(dst + (ty * 4 + i) * 64 + tx * 4) = v;
    }
}

__global__ __launch_bounds__(256) void k_redC(const float* __restrict__ pC, float* __restrict__ Tc)
{
    const int b = blockIdx.y;
    const int idx = blockIdx.x * 256 + threadIdx.x;
    const float* p = pC + (size_t)b * NKC * 4096 + idx;
    float acc = 0.f;
#pragma unroll
    for (int k = 0; k < NKC; k++) acc += p[(size_t)k * 4096];
    Tc[(size_t)b * 4096 + idx] = acc;
}

__global__ __launch_bounds__(1024) void k_softC(float* __restrict__ Tc)
{
    __shared__ float red[16 * 65];
    const int b = blockIdx.x;
    const int t = threadIdx.x;
    const int dc = t & 63, cg = t >> 6;
    float* S = Tc + (size_t)b * 4096 + dc;

    float v[4];
    float m = -3.4e38f;
#pragma unroll
    for (int j = 0; j < 4; j++) { v[j] = S[(cg * 4 + j) * 64]; m = fmaxf(m, v[j]); }
    red[cg * 65 + dc] = m;
    __syncthreads();
    for (int st = 8; st > 0; st >>= 1) {
        if (cg < st) red[cg * 65 + dc] = fmaxf(red[cg * 65 + dc], red[(cg + st) * 65 + dc]);
        __syncthreads();
    }
    m = red[dc];
    __syncthreads();
    float sum = 0.f;
#pragma unroll
    for (int j = 0; j < 4; j++) { v[j] = __expf(v[j] - m); sum += v[j]; }
    red[cg * 65 + dc] = sum;
    __syncthreads();
    for (int st = 8; st > 0; st >>= 1) {
        if (cg < st) red[cg * 65 + dc] += red[(cg + st) * 65 + dc];
        __syncthreads();
    }
    const float inv = 1.f / red[dc];
#pragma unroll
    for (int j = 0; j < 4; j++) S[(cg * 4 + j) * 64] = v[j] * inv;
}

// ---------------- Co: s_flat[b][n*64+d] = detal * sum_c inp[b,c,n]*Tc[c,d] ----------------
__global__ __launch_bounds__(256) void k_co(
    const float* __restrict__ inp, const float* __restrict__ Tc,
    const float* __restrict__ detal, float* __restrict__ s)
{
    __shared__ float tc[64 * 68];
    __shared__ float xs[64 * 132];
    const int b  = blockIdx.y;
    const int n0 = blockIdx.x * 128;
    const int t  = threadIdx.x;
    const int d4 = (t & 15) * 4;
    const int g8 = (t >> 4) * 8;

    {
        const int sr = t >> 2, sc = (t & 3) * 4;
        const float* src = inp + ((size_t)b * CC + sr) * NN + n0;
        float* dst = xs + sr * 132;
#pragma unroll
        for (int k = 0; k < 8; k++)
            *(float4*)(dst + sc + 16 * k) = *(const float4*)(src + sc + 16 * k);
        const float* tsrc = Tc + (size_t)b * 4096 + sr * 64;
        float* tdst = tc + sr * 68;
#pragma unroll
        for (int k = 0; k < 4; k++)
            *(float4*)(tdst + sc + 16 * k) = *(const float4*)(tsrc + sc + 16 * k);
    }
    __syncthreads();

    float acc[8][4];
#pragma unroll
    for (int i = 0; i < 8; i++)
#pragma unroll
        for (int j = 0; j < 4; j++) acc[i][j] = 0.f;

#pragma unroll 4
    for (int c = 0; c < 64; c++) {
        const float4 t4 = *(const float4*)(tc + c * 68 + d4);
        const float4 xa = *(const float4*)(xs + c * 132 + g8);
        const float4 xb = *(const float4*)(xs + c * 132 + g8 + 4);
        const float xv[8] = {xa.x, xa.y, xa.z, xa.w, xb.x, xb.y, xb.z, xb.w};
        const float tv[4] = {t4.x, t4.y, t4.z, t4.w};
#pragma unroll
        for (int i = 0; i < 8; i++)
#pragma unroll
            for (int j = 0; j < 4; j++) acc[i][j] += xv[i] * tv[j];
    }
    const float scl = detal[0];
    float* sb = s + (size_t)b * CC * NN + (size_t)n0 * 64;
#pragma unroll
    for (int i = 0; i < 8; i++) {
        float4 v = make_float4(acc[i][0] * scl, acc[i][1] * scl,
                               acc[i][2] * scl, acc[i][3] * scl);
        *(float4*)(sb + (size_t)(g8 + i) * 64 + d4) = v;
    }
}

// ---------------- Wo (==Ho): s[b,c,h,v] += 2*detal * sum_w inp[b,c,h,w]*Tw[w,v] ----------------
__global__ __launch_bounds__(128) void k_wo(
    const float* __restrict__ inp, const float* __restrict__ Tw,
    const float* __restrict__ detal, float* __restrict__ s)
{
    __shared__ float xt[32 * 68];
    __shared__ float twl[32 * 132];
    const int b = blockIdx.z, hc = blockIdx.y, c = blockIdx.x;
    const int t = threadIdx.x;
    const int rg = t >> 4;
    const int vg = t & 15;
    const int h0 = hc * 64;

    const float* ip = inp + ((size_t)b * CC + c) * NN + (size_t)h0 * WW;
    const float* twg = Tw + (size_t)b * 16384;

    float acc[8][8];
#pragma unroll
    for (int p = 0; p < 8; p++)
#pragma unroll
        for (int q = 0; q < 8; q++) acc[p][q] = 0.f;

    for (int w0 = 0; w0 < 128; w0 += 32) {
        __syncthreads();
        {
            const int h = t >> 1, wq = (t & 1) * 16;
            const float* src = ip + (size_t)h * WW + w0 + wq;
            float v[16];
            *(float4*)(v)      = *(const float4*)(src);
            *(float4*)(v + 4)  = *(const float4*)(src + 4);
            *(float4*)(v + 8)  = *(const float4*)(src + 8);
            *(float4*)(v + 12) = *(const float4*)(src + 12);
#pragma unroll
            for (int j = 0; j < 16; j++) xt[(wq + j) * 68 + h] = v[j];
        }
        {
            const int w = t >> 2, cq = (t & 3) * 32;
            const float* src = twg + (size_t)(w0 + w) * 128 + cq;
            float* dst = twl + w * 132 + cq;
#pragma unroll
            for (int k = 0; k < 8; k++)
                *(float4*)(dst + 4 * k) = *(const float4*)(src + 4 * k);
        }
        __syncthreads();
#pragma unroll 4
        for (int w = 0; w < 32; ++w) {
            const float4 ra = *(const float4*)(xt + w * 68 + rg * 8);
            const float4 rb = *(const float4*)(xt + w * 68 + rg * 8 + 4);
            const float4 ta = *(const float4*)(twl + w * 132 + vg * 4);
            const float4 tb = *(const float4*)(twl + w * 132 + 64 + vg * 4);
            const float rv[8] = {ra.x, ra.y, ra.z, ra.w, rb.x, rb.y, rb.z, rb.w};
            const float tv[8] = {ta.x, ta.y, ta.z, ta.w, tb.x, tb.y, tb.z, tb.w};
#pragma unroll
            for (int p = 0; p < 8; p++)
#pragma unroll
                for (int q = 0; q < 8; q++) acc[p][q] += rv[p] * tv[q];
        }
    }

    const float sc2 = 2.0f * detal[0];
    float* sp = s + ((size_t)b * CC + c) * NN + (size_t)h0 * WW;
#pragma unroll
    for (int p = 0; p < 8; ++p) {
        const int h = rg * 8 + p;
        float* q0 = sp + (size_t)h * WW + vg * 4;
        float* q1 = sp + (size_t)h * WW + 64 + vg * 4;
        float4 c0 = *(const float4*)q0;
        float4 c1 = *(const float4*)q1;
        c0.x += sc2 * acc[p][0]; c0.y += sc2 * acc[p][1];
        c0.z += sc2 * acc[p][2]; c0.w += sc2 * acc[p][3];
        c1.x += sc2 * acc[p][4]; c1.y += sc2 * acc[p][5];
        c1.z += sc2 * acc[p][6]; c1.w += sc2 * acc[p][7];
        *(float4*)q0 = c0;
        *(float4*)q1 = c1;
    }
}

// ---------------- outconv via MFMA fp16: out = w_out·s + b_out + x ----------------
// grid (NN/64, NB), block 256 (4 waves). Tile 256o x 64n, K=64 in 2 chunks of 32.
// W (256x64 fp16, 37KB) in LDS once; s-chunk cvt'd fp16 [c][72]. s read exactly once.
// HBM floor ~302MB (s 34 + x 134 + out 134) = 48us; MFMA compute ~3us.
__global__ __launch_bounds__(256) void k_outconv(
    const float* __restrict__ s, const _Float16* __restrict__ woh,
    const float* __restrict__ b_out, const float* __restrict__ x,
    float* __restrict__ outp)
{
    __shared__ _Float16 wo[256 * 72];   // [o][c], stride 72
    __shared__ _Float16 sh[32 * 72];    // [c][n], stride 72
    const int b  = blockIdx.y;
    const int n0 = blockIdx.x * 64;
    const int t  = threadIdx.x;
    const int l  = t & 63, wv = t >> 6;
    const int lr = l & 15, kg = (l >> 4) * 8;

    {   // load W once: 256 rows x 64 halves
        const uint4* src = (const uint4*)(woh + t * 64);
        uint4* dst = (uint4*)(wo + t * 72);
#pragma unroll
        for (int k = 0; k < 4; k++) dst[k] = src[k];
        const uint4* src2 = src + 4;
        uint4* dst2 = dst + 4;
#pragma unroll
        for (int k = 0; k < 4; k++) dst2[k] = src2[k];
    }

    f32x4 acc[4][4];
#pragma unroll
    for (int mt = 0; mt < 4; mt++)
#pragma unroll
        for (int nt = 0; nt < 4; nt++) acc[mt][nt] = (f32x4){0.f, 0.f, 0.f, 0.f};

    for (int kc = 0; kc < 2; ++kc) {
        __syncthreads();
        {   // stage s chunk: 32 c x 64 n fp32 -> fp16
            const int c = t >> 3, n8 = (t & 7) * 8;
            const float* src = s + ((size_t)b * CC + kc * 32 + c) * NN + n0 + n8;
            const float4 v0 = *(const float4*)(src);
            const float4 v1 = *(const float4*)(src + 4);
            f16x8 h;
            h[0] = (_Float16)v0.x; h[1] = (_Float16)v0.y;
            h[2] = (_Float16)v0.z; h[3] = (_Float16)v0.w;
            h[4] = (_Float16)v1.x; h[5] = (_Float16)v1.y;
            h[6] = (_Float16)v1.z; h[7] = (_Float16)v1.w;
            *(f16x8*)(sh + c * 72 + n8) = h;
        }
        __syncthreads();

        f16x8 bf[4];
#pragma unroll
        for (int nt = 0; nt < 4; ++nt) {
            const int n = nt * 16 + lr;
#pragma unroll
            for (int j = 0; j < 8; ++j) bf[nt][j] = sh[(kg + j) * 72 + n];
        }
#pragma unroll
        for (int mt = 0; mt < 4; ++mt) {
            const f16x8 af = *(const f16x8*)(wo + (wv * 64 + mt * 16 + lr) * 72 + kc * 32 + kg);
#pragma unroll
            for (int nt = 0; nt < 4; ++nt)
                acc[mt][nt] = __builtin_amdgcn_mfma_f32_16x16x32_f16(af, bf[nt], acc[mt][nt], 0, 0, 0);
        }
    }

#pragma unroll
    for (int mt = 0; mt < 4; ++mt)
#pragma unroll
        for (int nt = 0; nt < 4; ++nt) {
            const int n = n0 + nt * 16 + lr;
#pragma unroll
            for (int r = 0; r < 4; ++r) {
                const int o = wv * 64 + mt * 16 + (l >> 4) * 4 + r;
                const size_t off = ((size_t)b * IC + o) * NN + n;
                outp[off] = (float)acc[mt][nt][r] + b_out[o] + x[off];
            }
        }
}

extern "C" void kernel_launch(void* const* d_in, const int* in_sizes, int n_in,
                              void* d_out, int out_size, void* d_ws, size_t ws_size,
                              hipStream_t stream)
{
    const float* x     = (const float*)d_in[0];
    const float* w_in  = (const float*)d_in[1];
    const float* b_in  = (const float*)d_in[2];
    const float* w_out = (const float*)d_in[3];
    const float* b_out = (const float*)d_in[4];
    const float* detal = (const float*)d_in[5];
    float* out = (float*)d_out;

    float* ws   = (float*)d_ws;
    float* inp  = ws + OFF_INP;
    float* s    = ws + OFF_S;
    float* pW   = ws + OFF_S;      // aliased with s (pW dead before k_co writes s)
    float* pC   = ws + OFF_PC;
    float* Tw   = ws + OFF_TW;
    float* Tc   = ws + OFF_TC;
    _Float16* wh  = (_Float16*)(ws + OFF_WT);
    _Float16* woh = (_Float16*)(ws + OFF_WOT);

    k_wt     <<<dim3(128),              256, 0, stream>>>(w_in, w_out, wh, woh);
    k_inconv <<<dim3(NN / 128, NB),     256, 0, stream>>>(x, wh, b_in, inp);
    k_gramW  <<<dim3(NKW, NB),          256, 0, stream>>>(inp, pW);
    k_redW   <<<dim3(64, NB),           256, 0, stream>>>(pW, Tw);
    k_softW  <<<dim3(NB, 4),           1024, 0, stream>>>(Tw);
    k_gramC  <<<dim3(NKC, NB),          256, 0, stream>>>(inp, pC);
    k_redC   <<<dim3(16, NB),           256, 0, stream>>>(pC, Tc);
    k_softC  <<<dim3(NB),              1024, 0, stream>>>(Tc);
    k_co     <<<dim3(NN / 128, NB),     256, 0, stream>>>(inp, Tc, detal, s);
    k_wo     <<<dim3(CC, 2, NB),        128, 0, stream>>>(inp, Tw, detal, s);
    k_outconv<<<dim3(NN / 64, NB),      256, 0, stream>>>(s, woh, b_out, x, out);
}

// Round 12
// 413.650 us; speedup vs baseline: 1.0764x; 1.0764x over previous
//
#include <hip/hip_runtime.h>
#include <math.h>

#define NB 8
#define IC 256
#define CC 64
#define HH 128
#define WW 128
#define NN (HH*WW)      // 16384
#define NKW 64
#define NKC 64

typedef _Float16 f16x8 __attribute__((ext_vector_type(8)));
typedef float f32x4 __attribute__((ext_vector_type(4)));

// ---------------- workspace layout (floats) ----------------
static constexpr size_t SZ_INP  = (size_t)NB * CC * NN;            // 8,388,608
static constexpr size_t OFF_INP = 0;
static constexpr size_t OFF_S   = OFF_INP + SZ_INP;                // s AND pW (aliased)
static constexpr size_t OFF_PC  = OFF_S + SZ_INP;                  // pC: NB*NKC*4096
static constexpr size_t OFF_TW  = OFF_PC + (size_t)NB * NKC * 4096;
static constexpr size_t OFF_TC  = OFF_TW + (size_t)NB * 16384;
static constexpr size_t OFF_WT  = OFF_TC + (size_t)NB * 4096;      // w_in fp16 [64 o][256 i]
static constexpr size_t OFF_WOT = OFF_WT + 16384;                  // w_out fp16 [256 o][64 c]
static constexpr size_t OFF_TWT = OFF_WOT + 16384;                 // TwT fp16 [b][v 128][w 128]
static constexpr size_t OFF_TCT = OFF_TWT + 65536;                 // TcT fp16 [b][d 64][c 64]

// ---------------- weight fp16 casts ----------------
__global__ __launch_bounds__(256) void k_wt(
    const float* __restrict__ w_in, const float* __restrict__ w_out,
    _Float16* __restrict__ wh, _Float16* __restrict__ woh)
{
    const int idx = blockIdx.x * 256 + threadIdx.x;   // 0..32767
    if (idx < 16384) wh[idx] = (_Float16)w_in[idx];           // [o][i]
    else             woh[idx - 16384] = (_Float16)w_out[idx - 16384];  // [o][c]
}

// ---------------- inconv via MFMA fp16 (round-11, passed) ----------------
__global__ __launch_bounds__(256) void k_inconv(
    const float* __restrict__ x, const _Float16* __restrict__ wh,
    const float* __restrict__ b_in, float* __restrict__ inp)
{
    __shared__ __align__(16) _Float16 wl[64 * 264];
    __shared__ __align__(16) _Float16 xh[32 * 136];
    const int b  = blockIdx.y;
    const int n0 = blockIdx.x * 128;
    const int t  = threadIdx.x;
    const int l  = t & 63, wv = t >> 6;
    const int lr = l & 15, kg = (l >> 4) * 8;

    {   // load W once: 64 rows x 256 halves
        const int r = t >> 2, c = (t & 3) * 64;
        const uint4* src = (const uint4*)(wh + r * 256 + c);
        uint4* dst = (uint4*)(wl + r * 264 + c);
#pragma unroll
        for (int k = 0; k < 8; k++) dst[k] = src[k];
    }

    f32x4 acc[4][2];
#pragma unroll
    for (int mt = 0; mt < 4; mt++)
#pragma unroll
        for (int nt = 0; nt < 2; nt++) acc[mt][nt] = (f32x4){0.f, 0.f, 0.f, 0.f};

    for (int kc = 0; kc < 8; ++kc) {
        __syncthreads();
        {
            const int i = t >> 3, nq = (t & 7) * 16;
            const float* src = x + ((size_t)b * IC + kc * 32 + i) * NN + n0 + nq;
            const float4 v0 = *(const float4*)(src);
            const float4 v1 = *(const float4*)(src + 4);
            const float4 v2 = *(const float4*)(src + 8);
            const float4 v3 = *(const float4*)(src + 12);
            f16x8 h0, h1;
            h0[0] = (_Float16)v0.x; h0[1] = (_Float16)v0.y;
            h0[2] = (_Float16)v0.z; h0[3] = (_Float16)v0.w;
            h0[4] = (_Float16)v1.x; h0[5] = (_Float16)v1.y;
            h0[6] = (_Float16)v1.z; h0[7] = (_Float16)v1.w;
            h1[0] = (_Float16)v2.x; h1[1] = (_Float16)v2.y;
            h1[2] = (_Float16)v2.z; h1[3] = (_Float16)v2.w;
            h1[4] = (_Float16)v3.x; h1[5] = (_Float16)v3.y;
            h1[6] = (_Float16)v3.z; h1[7] = (_Float16)v3.w;
            *(f16x8*)(xh + i * 136 + nq)     = h0;
            *(f16x8*)(xh + i * 136 + nq + 8) = h1;
        }
        __syncthreads();

        f16x8 bf[2];
#pragma unroll
        for (int nt = 0; nt < 2; ++nt) {
            const int n = wv * 32 + nt * 16 + lr;
#pragma unroll
            for (int j = 0; j < 8; ++j) bf[nt][j] = xh[(kg + j) * 136 + n];
        }
#pragma unroll
        for (int mt = 0; mt < 4; ++mt) {
            const f16x8 af = *(const f16x8*)(wl + (mt * 16 + lr) * 264 + kc * 32 + kg);
            acc[mt][0] = __builtin_amdgcn_mfma_f32_16x16x32_f16(af, bf[0], acc[mt][0], 0, 0, 0);
            acc[mt][1] = __builtin_amdgcn_mfma_f32_16x16x32_f16(af, bf[1], acc[mt][1], 0, 0, 0);
        }
    }

#pragma unroll
    for (int mt = 0; mt < 4; ++mt)
#pragma unroll
        for (int nt = 0; nt < 2; ++nt) {
            const int n = n0 + wv * 32 + nt * 16 + lr;
#pragma unroll
            for (int r = 0; r < 4; ++r) {
                const int o = mt * 16 + (l >> 4) * 4 + r;
                inp[((size_t)b * CC + o) * NN + n] = (float)acc[mt][nt][r] + b_in[o];
            }
        }
}

// ---------------- gram W partials (fp32 — feeds softmax, keep precision) ----------------
__global__ __launch_bounds__(256) void k_gramW(const float* __restrict__ inp, float* __restrict__ pW)
{
    __shared__ float xs[32 * 132];
    const int b = blockIdx.y, kc = blockIdx.x;
    const int t = threadIdx.x, tx = t & 15, ty = t >> 4;
    const float* Xb = inp + (size_t)b * CC * NN;
    const int k0 = kc * ((CC * HH) / NKW);

    float acc[8][8];
#pragma unroll
    for (int i = 0; i < 8; i++)
#pragma unroll
        for (int j = 0; j < 8; j++) acc[i][j] = 0.f;

    for (int kk = k0; kk < k0 + (CC * HH) / NKW; kk += 32) {
        __syncthreads();
        {
            const int r = t >> 3, cq = (t & 7) * 16;
            const float* src = Xb + ((size_t)kk + r) * WW + cq;
            float* dst = xs + r * 132 + cq;
#pragma unroll
            for (int j = 0; j < 4; j++)
                *(float4*)(dst + 4 * j) = *(const float4*)(src + 4 * j);
        }
        __syncthreads();
#pragma unroll 8
        for (int k = 0; k < 32; k++) {
            const float* row = xs + k * 132;
            float4 t0 = *(const float4*)(row + ty * 8);
            float4 t1 = *(const float4*)(row + ty * 8 + 4);
            float4 u0 = *(const float4*)(row + tx * 8);
            float4 u1 = *(const float4*)(row + tx * 8 + 4);
            float av[8] = {t0.x, t0.y, t0.z, t0.w, t1.x, t1.y, t1.z, t1.w};
            float bv[8] = {u0.x, u0.y, u0.z, u0.w, u1.x, u1.y, u1.z, u1.w};
#pragma unroll
            for (int i = 0; i < 8; i++)
#pragma unroll
                for (int j = 0; j < 8; j++) acc[i][j] += av[i] * bv[j];
        }
    }
    float* dst = pW + ((size_t)b * NKW + kc) * 16384;
#pragma unroll
    for (int i = 0; i < 8; i++)
#pragma unroll
        for (int j = 0; j < 8; j += 4) {
            float4 v = make_float4(acc[i][j], acc[i][j + 1], acc[i][j + 2], acc[i][j + 3]);
            *(float4*)(dst + (ty * 8 + i) * 128 + tx * 8 + j) = v;
        }
}

__global__ __launch_bounds__(256) void k_redW(const float* __restrict__ pW, float* __restrict__ Tw)
{
    const int b = blockIdx.y;
    const int idx = blockIdx.x * 256 + threadIdx.x;
    const float* p = pW + (size_t)b * NKW * 16384 + idx;
    float acc = 0.f;
#pragma unroll
    for (int k = 0; k < NKW; k++) acc += p[(size_t)k * 16384];
    Tw[(size_t)b * 16384 + idx] = acc;
}

// softmax over w per column v; emits TwT fp16 [v][w] (k_wo's B operand); no fp32 writeback
__global__ __launch_bounds__(1024) void k_softW(const float* __restrict__ Tw, _Float16* __restrict__ twt)
{
    __shared__ float red[32 * 33];
    const int b = blockIdx.x, v0 = blockIdx.y * 32;
    const int t = threadIdx.x;
    const int vc = t & 31, wg = t >> 5;
    const float* S = Tw + (size_t)b * 16384 + v0 + vc;

    float v[4];
    float m = -3.4e38f;
#pragma unroll
    for (int j = 0; j < 4; j++) { v[j] = S[(wg * 4 + j) * 128]; m = fmaxf(m, v[j]); }
    red[wg * 33 + vc] = m;
    __syncthreads();
    for (int st = 16; st > 0; st >>= 1) {
        if (wg < st) red[wg * 33 + vc] = fmaxf(red[wg * 33 + vc], red[(wg + st) * 33 + vc]);
        __syncthreads();
    }
    m = red[vc];
    __syncthreads();
    float sum = 0.f;
#pragma unroll
    for (int j = 0; j < 4; j++) { v[j] = __expf(v[j] - m); sum += v[j]; }
    red[wg * 33 + vc] = sum;
    __syncthreads();
    for (int st = 16; st > 0; st >>= 1) {
        if (wg < st) red[wg * 33 + vc] += red[(wg + st) * 33 + vc];
        __syncthreads();
    }
    const float inv = 1.f / red[vc];
    _Float16* dst = twt + (size_t)b * 16384 + (size_t)(v0 + vc) * 128 + wg * 4;
#pragma unroll
    for (int j = 0; j < 4; j++) dst[j] = (_Float16)(v[j] * inv);
}

// ---------------- gram C partials (fp32 — feeds softmax, keep precision) ----------------
__global__ __launch_bounds__(256) void k_gramC(const float* __restrict__ inp, float* __restrict__ pC)
{
    __shared__ float xt[32 * 68];
    const int b = blockIdx.y, nc = blockIdx.x;
    const int t = threadIdx.x, tx = t & 15, ty = t >> 4;
    const float* ip = inp + (size_t)b * CC * NN;
    const int n0 = nc * (NN / NKC);

    float acc[4][4];
#pragma unroll
    for (int i = 0; i < 4; i++)
#pragma unroll
        for (int j = 0; j < 4; j++) acc[i][j] = 0.f;

    const int scc = t >> 2;
    const int sn  = (t & 3) * 8;

    for (int nt = 0; nt < NN / NKC; nt += 32) {
        __syncthreads();
        {
            const float* src = ip + (size_t)scc * NN + n0 + nt + sn;
            float v[8];
            *(float4*)(v)     = *(const float4*)(src);
            *(float4*)(v + 4) = *(const float4*)(src + 4);
#pragma unroll
            for (int j = 0; j < 8; j++) xt[(sn + j) * 68 + scc] = v[j];
        }
        __syncthreads();
#pragma unroll 8
        for (int nn = 0; nn < 32; nn++) {
            const float4 a4 = *(const float4*)(xt + nn * 68 + ty * 4);
            const float4 e4 = *(const float4*)(xt + nn * 68 + tx * 4);
            const float av[4] = {a4.x, a4.y, a4.z, a4.w};
            const float ev[4] = {e4.x, e4.y, e4.z, e4.w};
#pragma unroll
            for (int i = 0; i < 4; i++)
#pragma unroll
                for (int j = 0; j < 4; j++) acc[i][j] += av[i] * ev[j];
        }
    }
    float* dst = pC + ((size_t)b * NKC + nc) * 4096;
#pragma unroll
    for (int i = 0; i < 4; i++) {
        float4 v = make_float4(acc[i][0], acc[i][1], acc[i][2], acc[i][3]);
        *(float4*)(dst + (ty * 4 + i) * 64 + tx * 4) = v;
    }
}

__global__ __launch_bounds__(256) void k_redC(const float* __restrict__ pC, float* __restrict__ Tc)
{
    const int b = blockIdx.y;
    const int idx = blockIdx.x * 256 + threadIdx.x;
    const float* p = pC + (size_t)b * NKC * 4096 + idx;
    float acc = 0.f;
#pragma unroll
    for (int k = 0; k < NKC; k++) acc += p[(size_t)k * 4096];
    Tc[(size_t)b * 4096 + idx] = acc;
}

// softmax over c per column d; emits TcT fp16 [d][c]; no fp32 writeback
__global__ __launch_bounds__(1024) void k_softC(const float* __restrict__ Tc, _Float16* __restrict__ tct)
{
    __shared__ float red[16 * 65];
    const int b = blockIdx.x;
    const int t = threadIdx.x;
    const int dc = t & 63, cg = t >> 6;
    const float* S = Tc + (size_t)b * 4096 + dc;

    float v[4];
    float m = -3.4e38f;
#pragma unroll
    for (int j = 0; j < 4; j++) { v[j] = S[(cg * 4 + j) * 64]; m = fmaxf(m, v[j]); }
    red[cg * 65 + dc] = m;
    __syncthreads();
    for (int st = 8; st > 0; st >>= 1) {
        if (cg < st) red[cg * 65 + dc] = fmaxf(red[cg * 65 + dc], red[(cg + st) * 65 + dc]);
        __syncthreads();
    }
    m = red[dc];
    __syncthreads();
    float sum = 0.f;
#pragma unroll
    for (int j = 0; j < 4; j++) { v[j] = __expf(v[j] - m); sum += v[j]; }
    red[cg * 65 + dc] = sum;
    __syncthreads();
    for (int st = 8; st > 0; st >>= 1) {
        if (cg < st) red[cg * 65 + dc] += red[(cg + st) * 65 + dc];
        __syncthreads();
    }
    const float inv = 1.f / red[dc];
    _Float16* dst = tct + (size_t)b * 4096 + (size_t)dc * 64 + cg * 4;
#pragma unroll
    for (int j = 0; j < 4; j++) dst[j] = (_Float16)(v[j] * inv);
}

// ---------------- Co via MFMA fp16: s_flat[b][n*64+d] = detal * sum_c inp[b,c,n]*Tc[c,d] ----------------
// grid (NN/128, NB), block 256 (4 waves). Tile 128n x 64d, K=64 staged once (1 barrier).
// inp^T staged fp16 [n][72] via per-j coalesced scalar loads; TcT fp16 from global (8KB/b, L2).
// A row=n (k=c contig), B col=d (TcT rows k-contig). HBM ~67MB -> ~11us floor.
__global__ __launch_bounds__(256) void k_co(
    const float* __restrict__ inp, const _Float16* __restrict__ tct,
    const float* __restrict__ detal, float* __restrict__ s)
{
    __shared__ __align__(16) _Float16 xh[128 * 72];   // [n][c], stride 72
    __shared__ __align__(16) _Float16 tl[64 * 72];    // [d][c], stride 72
    const int b  = blockIdx.y;
    const int n0 = blockIdx.x * 128;
    const int t  = threadIdx.x;
    const int l  = t & 63, wv = t >> 6;
    const int lr = l & 15, kg = (l >> 4) * 8;

    {   // stage inp^T: thread owns one n, half the c-range; per-j loads are wave-coalesced along n
        const int nn = t & 127, ch = t >> 7;   // ch: c in [ch*32, ch*32+32)
        const float* src = inp + ((size_t)b * CC + ch * 32) * NN + n0 + nn;
#pragma unroll
        for (int k2 = 0; k2 < 4; ++k2) {
            float f[8];
#pragma unroll
            for (int j = 0; j < 8; ++j) f[j] = src[(size_t)(k2 * 8 + j) * NN];
            f16x8 h;
#pragma unroll
            for (int j = 0; j < 8; ++j) h[j] = (_Float16)f[j];
            *(f16x8*)(xh + nn * 72 + ch * 32 + k2 * 8) = h;
        }
    }
    {   // stage TcT: 64 x 64 halves
        const int d = t >> 2, cq = (t & 3) * 16;
        const _Float16* src = tct + (size_t)b * 4096 + d * 64 + cq;
        *(uint4*)(tl + d * 72 + cq)     = *(const uint4*)(src);
        *(uint4*)(tl + d * 72 + cq + 8) = *(const uint4*)(src + 8);
    }
    __syncthreads();

    f32x4 acc[2][4];
#pragma unroll
    for (int mt = 0; mt < 2; mt++)
#pragma unroll
        for (int nt = 0; nt < 4; nt++) acc[mt][nt] = (f32x4){0.f, 0.f, 0.f, 0.f};

#pragma unroll
    for (int kc = 0; kc < 2; ++kc) {
        f16x8 bf[4];
#pragma unroll
        for (int nt = 0; nt < 4; ++nt)
            bf[nt] = *(const f16x8*)(tl + (nt * 16 + lr) * 72 + kc * 32 + kg);
#pragma unroll
        for (int mt = 0; mt < 2; ++mt) {
            const f16x8 af = *(const f16x8*)(xh + (wv * 32 + mt * 16 + lr) * 72 + kc * 32 + kg);
#pragma unroll
            for (int nt = 0; nt < 4; ++nt)
                acc[mt][nt] = __builtin_amdgcn_mfma_f32_16x16x32_f16(af, bf[nt], acc[mt][nt], 0, 0, 0);
        }
    }

    const float scl = detal[0];
    float* sb = s + (size_t)b * CC * NN;
#pragma unroll
    for (int mt = 0; mt < 2; ++mt)
#pragma unroll
        for (int nt = 0; nt < 4; ++nt) {
            const int d = nt * 16 + lr;
#pragma unroll
            for (int r = 0; r < 4; ++r) {
                const int n = n0 + wv * 32 + mt * 16 + (l >> 4) * 4 + r;
                sb[(size_t)n * 64 + d] = scl * acc[mt][nt][r];
            }
        }
}

// ---------------- Wo (==Ho) via MFMA fp16: s[b,c,h,v] += 2*detal * sum_w inp[b,c,h,w]*Tw[w,v] ----------------
// grid (CC, 2, NB), block 256 (4 waves). Tile 64h x 128v, K=128 staged once (1 barrier).
// X cvt-staged [h][136] (k=w contig); TwT fp16 [v][136] copied from global (256KB/b, L2).
__global__ __launch_bounds__(256) void k_wo(
    const float* __restrict__ inp, const _Float16* __restrict__ twt,
    const float* __restrict__ detal, float* __restrict__ s)
{
    __shared__ __align__(16) _Float16 xh[64 * 136];    // [h][w], stride 136
    __shared__ __align__(16) _Float16 tl[128 * 136];   // [v][w], stride 136
    const int b = blockIdx.z, hc = blockIdx.y, c = blockIdx.x;
    const int t = threadIdx.x;
    const int l = t & 63, wv = t >> 6;
    const int lr = l & 15, kg = (l >> 4) * 8;
    const int h0 = hc * 64;

    const float* ip = inp + ((size_t)b * CC + c) * NN + (size_t)h0 * WW;

    {   // stage X fp16: thread owns h=t>>2, 32 w's
        const int h = t >> 2, wq = (t & 3) * 32;
        const float* src = ip + (size_t)h * WW + wq;
#pragma unroll
        for (int k2 = 0; k2 < 4; ++k2) {
            const float4 v0 = *(const float4*)(src + k2 * 8);
            const float4 v1 = *(const float4*)(src + k2 * 8 + 4);
            f16x8 h8;
            h8[0] = (_Float16)v0.x; h8[1] = (_Float16)v0.y;
            h8[2] = (_Float16)v0.z; h8[3] = (_Float16)v0.w;
            h8[4] = (_Float16)v1.x; h8[5] = (_Float16)v1.y;
            h8[6] = (_Float16)v1.z; h8[7] = (_Float16)v1.w;
            *(f16x8*)(xh + h * 136 + wq + k2 * 8) = h8;
        }
    }
    {   // stage TwT: thread owns v=t>>1, 64 w's
        const int v = t >> 1, wh2 = (t & 1) * 64;
        const _Float16* src = twt + (size_t)b * 16384 + (size_t)v * 128 + wh2;
        uint4* dst = (uint4*)(tl + v * 136 + wh2);
#pragma unroll
        for (int k = 0; k < 8; ++k) dst[k] = *(const uint4*)(src + 8 * k);
    }
    __syncthreads();

    f32x4 acc[8];
#pragma unroll
    for (int nt = 0; nt < 8; nt++) acc[nt] = (f32x4){0.f, 0.f, 0.f, 0.f};

#pragma unroll
    for (int kc = 0; kc < 4; ++kc) {
        const f16x8 af = *(const f16x8*)(xh + (wv * 16 + lr) * 136 + kc * 32 + kg);
#pragma unroll
        for (int nt = 0; nt < 8; ++nt) {
            const f16x8 bf = *(const f16x8*)(tl + (nt * 16 + lr) * 136 + kc * 32 + kg);
            acc[nt] = __builtin_amdgcn_mfma_f32_16x16x32_f16(af, bf, acc[nt], 0, 0, 0);
        }
    }

    const float sc2 = 2.0f * detal[0];
    float* sp = s + ((size_t)b * CC + c) * NN + (size_t)h0 * WW;
#pragma unroll
    for (int nt = 0; nt < 8; ++nt) {
        const int v = nt * 16 + lr;
#pragma unroll
        for (int r = 0; r < 4; ++r) {
            const int h = wv * 16 + (l >> 4) * 4 + r;
            float* p = sp + (size_t)h * WW + v;
            *p = *p + sc2 * acc[nt][r];
        }
    }
}

// ---------------- outconv via MFMA fp16 (round-11, passed) ----------------
__global__ __launch_bounds__(256) void k_outconv(
    const float* __restrict__ s, const _Float16* __restrict__ woh,
    const float* __restrict__ b_out, const float* __restrict__ x,
    float* __restrict__ outp)
{
    __shared__ __align__(16) _Float16 wo[256 * 72];
    __shared__ __align__(16) _Float16 sh[32 * 72];
    const int b  = blockIdx.y;
    const int n0 = blockIdx.x * 64;
    const int t  = threadIdx.x;
    const int l  = t & 63, wv = t >> 6;
    const int lr = l & 15, kg = (l >> 4) * 8;

    {   // load W once: 256 rows x 64 halves
        const uint4* src = (const uint4*)(woh + t * 64);
        uint4* dst = (uint4*)(wo + t * 72);
#pragma unroll
        for (int k = 0; k < 8; k++) dst[k] = src[k];
    }

    f32x4 acc[4][4];
#pragma unroll
    for (int mt = 0; mt < 4; mt++)
#pragma unroll
        for (int nt = 0; nt < 4; nt++) acc[mt][nt] = (f32x4){0.f, 0.f, 0.f, 0.f};

    for (int kc = 0; kc < 2; ++kc) {
        __syncthreads();
        {
            const int c = t >> 3, n8 = (t & 7) * 8;
            const float* src = s + ((size_t)b * CC + kc * 32 + c) * NN + n0 + n8;
            const float4 v0 = *(const float4*)(src);
            const float4 v1 = *(const float4*)(src + 4);
            f16x8 h;
            h[0] = (_Float16)v0.x; h[1] = (_Float16)v0.y;
            h[2] = (_Float16)v0.z; h[3] = (_Float16)v0.w;
            h[4] = (_Float16)v1.x; h[5] = (_Float16)v1.y;
            h[6] = (_Float16)v1.z; h[7] = (_Float16)v1.w;
            *(f16x8*)(sh + c * 72 + n8) = h;
        }
        __syncthreads();

        f16x8 bf[4];
#pragma unroll
        for (int nt = 0; nt < 4; ++nt) {
            const int n = nt * 16 + lr;
#pragma unroll
            for (int j = 0; j < 8; ++j) bf[nt][j] = sh[(kg + j) * 72 + n];
        }
#pragma unroll
        for (int mt = 0; mt < 4; ++mt) {
            const f16x8 af = *(const f16x8*)(wo + (wv * 64 + mt * 16 + lr) * 72 + kc * 32 + kg);
#pragma unroll
            for (int nt = 0; nt < 4; ++nt)
                acc[mt][nt] = __builtin_amdgcn_mfma_f32_16x16x32_f16(af, bf[nt], acc[mt][nt], 0, 0, 0);
        }
    }

#pragma unroll
    for (int mt = 0; mt < 4; ++mt)
#pragma unroll
        for (int nt = 0; nt < 4; ++nt) {
            const int n = n0 + nt * 16 + lr;
#pragma unroll
            for (int r = 0; r < 4; ++r) {
                const int o = wv * 64 + mt * 16 + (l >> 4) * 4 + r;
                const size_t off = ((size_t)b * IC + o) * NN + n;
                outp[off] = (float)acc[mt][nt][r] + b_out[o] + x[off];
            }
        }
}

extern "C" void kernel_launch(void* const* d_in, const int* in_sizes, int n_in,
                              void* d_out, int out_size, void* d_ws, size_t ws_size,
                              hipStream_t stream)
{
    const float* x     = (const float*)d_in[0];
    const float* w_in  = (const float*)d_in[1];
    const float* b_in  = (const float*)d_in[2];
    const float* w_out = (const float*)d_in[3];
    const float* b_out = (const float*)d_in[4];
    const float* detal = (const float*)d_in[5];
    float* out = (float*)d_out;

    float* ws   = (float*)d_ws;
    float* inp  = ws + OFF_INP;
    float* s    = ws + OFF_S;
    float* pW   = ws + OFF_S;      // aliased with s (pW dead before k_co writes s)
    float* pC   = ws + OFF_PC;
    float* Tw   = ws + OFF_TW;
    float* Tc   = ws + OFF_TC;
    _Float16* wh  = (_Float16*)(ws + OFF_WT);
    _Float16* woh = (_Float16*)(ws + OFF_WOT);
    _Float16* twt = (_Float16*)(ws + OFF_TWT);
    _Float16* tct = (_Float16*)(ws + OFF_TCT);

    k_wt     <<<dim3(128),              256, 0, stream>>>(w_in, w_out, wh, woh);
    k_inconv <<<dim3(NN / 128, NB),     256, 0, stream>>>(x, wh, b_in, inp);
    k_gramW  <<<dim3(NKW, NB),          256, 0, stream>>>(inp, pW);
    k_redW   <<<dim3(64, NB),           256, 0, stream>>>(pW, Tw);
    k_softW  <<<dim3(NB, 4),           1024, 0, stream>>>(Tw, twt);
    k_gramC  <<<dim3(NKC, NB),          256, 0, stream>>>(inp, pC);
    k_redC   <<<dim3(16, NB),           256, 0, stream>>>(pC, Tc);
    k_softC  <<<dim3(NB),              1024, 0, stream>>>(Tc, tct);
    k_co     <<<dim3(NN / 128, NB),     256, 0, stream>>>(inp, tct, detal, s);
    k_wo     <<<dim3(CC, 2, NB),        256, 0, stream>>>(inp, twt, detal, s);
    k_outconv<<<dim3(NN / 64, NB),      256, 0, stream>>>(s, woh, b_out, x, out);
}

// Round 13
// 411.657 us; speedup vs baseline: 1.0816x; 1.0048x over previous
//
#include <hip/hip_runtime.h>
#include <math.h>

#define NB 8
#define IC 256
#define CC 64
#define HH 128
#define WW 128
#define NN (HH*WW)      // 16384
#define NKW 64
#define NKC 64

typedef _Float16 f16x8 __attribute__((ext_vector_type(8)));
typedef float f32x4 __attribute__((ext_vector_type(4)));

// ---------------- workspace layout (floats) ----------------
static constexpr size_t SZ_INP  = (size_t)NB * CC * NN;            // 8,388,608
static constexpr size_t OFF_INP = 0;
static constexpr size_t OFF_S   = OFF_INP + SZ_INP;                // s AND pW (aliased)
static constexpr size_t OFF_PC  = OFF_S + SZ_INP;                  // pC: NB*NKC*4096
static constexpr size_t OFF_TW  = OFF_PC + (size_t)NB * NKC * 4096;
static constexpr size_t OFF_TC  = OFF_TW + (size_t)NB * 16384;
static constexpr size_t OFF_WT  = OFF_TC + (size_t)NB * 4096;      // w_in fp16 [64 o][256 i]
static constexpr size_t OFF_WOT = OFF_WT + 16384;                  // w_out fp16 [256 o][64 c]
static constexpr size_t OFF_TWT = OFF_WOT + 16384;                 // TwT fp16 [b][v 128][w 128]
static constexpr size_t OFF_TCT = OFF_TWT + 65536;                 // TcT fp16 [b][d 64][c 64]

// ---------------- weight fp16 casts ----------------
__global__ __launch_bounds__(256) void k_wt(
    const float* __restrict__ w_in, const float* __restrict__ w_out,
    _Float16* __restrict__ wh, _Float16* __restrict__ woh)
{
    const int idx = blockIdx.x * 256 + threadIdx.x;   // 0..32767
    if (idx < 16384) wh[idx] = (_Float16)w_in[idx];           // [o][i]
    else             woh[idx - 16384] = (_Float16)w_out[idx - 16384];  // [o][c]
}

// ---------------- inconv via MFMA fp16: inp[b,o,n] = sum_i w[o,i]*x[b,i,n] + b_in[o] ----------------
// grid (NN/128, NB), block 256 (4 waves). Tile 64o x 128n, K=256 in 4 chunks of 64.
// x staged TRANSPOSED fp16 [n][72] (per-lane scalar global reads, coalesced along n) so
// every B-fragment is ONE ds_read_b128 — round-12's [k][n] layout cost 16 ds_read_u16
// per wave per chunk (~93cy vs 40cy MFMA, LDS-issue-bound). W [o][264] in LDS once.
__global__ __launch_bounds__(256) void k_inconv(
    const float* __restrict__ x, const _Float16* __restrict__ wh,
    const float* __restrict__ b_in, float* __restrict__ inp)
{
    __shared__ __align__(16) _Float16 wl[64 * 264];   // [o][i]
    __shared__ __align__(16) _Float16 xh[128 * 72];   // [n][i-chunk 64], stride 72
    const int b  = blockIdx.y;
    const int n0 = blockIdx.x * 128;
    const int t  = threadIdx.x;
    const int l  = t & 63, wv = t >> 6;
    const int lr = l & 15, kg = (l >> 4) * 8;

    {   // load W once: 64 rows x 256 halves
        const int r = t >> 2, c = (t & 3) * 64;
        const uint4* src = (const uint4*)(wh + r * 256 + c);
        uint4* dst = (uint4*)(wl + r * 264 + c);
#pragma unroll
        for (int k = 0; k < 8; k++) dst[k] = src[k];
    }

    f32x4 acc[4][2];
#pragma unroll
    for (int mt = 0; mt < 4; mt++)
#pragma unroll
        for (int nt = 0; nt < 2; nt++) acc[mt][nt] = (f32x4){0.f, 0.f, 0.f, 0.f};

    for (int kc = 0; kc < 4; ++kc) {
        __syncthreads();
        {   // stage x^T chunk: thread owns n=t&127, i-range (t>>7)*32..+31
            const int nn = t & 127, ch = t >> 7;
            const float* src = x + ((size_t)b * IC + kc * 64 + ch * 32) * NN + n0 + nn;
#pragma unroll
            for (int k2 = 0; k2 < 4; ++k2) {
                float f[8];
#pragma unroll
                for (int j = 0; j < 8; ++j) f[j] = src[(size_t)(k2 * 8 + j) * NN];
                f16x8 h;
#pragma unroll
                for (int j = 0; j < 8; ++j) h[j] = (_Float16)f[j];
                *(f16x8*)(xh + nn * 72 + ch * 32 + k2 * 8) = h;
            }
        }
        __syncthreads();

#pragma unroll
        for (int kk = 0; kk < 2; ++kk) {     // two K=32 frag-groups within the 64-chunk
            f16x8 bf[2];
#pragma unroll
            for (int nt = 0; nt < 2; ++nt)
                bf[nt] = *(const f16x8*)(xh + (wv * 32 + nt * 16 + lr) * 72 + kk * 32 + kg);
#pragma unroll
            for (int mt = 0; mt < 4; ++mt) {
                const f16x8 af = *(const f16x8*)(wl + (mt * 16 + lr) * 264 + kc * 64 + kk * 32 + kg);
                acc[mt][0] = __builtin_amdgcn_mfma_f32_16x16x32_f16(af, bf[0], acc[mt][0], 0, 0, 0);
                acc[mt][1] = __builtin_amdgcn_mfma_f32_16x16x32_f16(af, bf[1], acc[mt][1], 0, 0, 0);
            }
        }
    }

#pragma unroll
    for (int mt = 0; mt < 4; ++mt)
#pragma unroll
        for (int nt = 0; nt < 2; ++nt) {
            const int n = n0 + wv * 32 + nt * 16 + lr;
#pragma unroll
            for (int r = 0; r < 4; ++r) {
                const int o = mt * 16 + (l >> 4) * 4 + r;
                inp[((size_t)b * CC + o) * NN + n] = (float)acc[mt][nt][r] + b_in[o];
            }
        }
}

// ---------------- gram W partials (fp32 — feeds softmax, keep precision) ----------------
__global__ __launch_bounds__(256) void k_gramW(const float* __restrict__ inp, float* __restrict__ pW)
{
    __shared__ float xs[32 * 132];
    const int b = blockIdx.y, kc = blockIdx.x;
    const int t = threadIdx.x, tx = t & 15, ty = t >> 4;
    const float* Xb = inp + (size_t)b * CC * NN;
    const int k0 = kc * ((CC * HH) / NKW);

    float acc[8][8];
#pragma unroll
    for (int i = 0; i < 8; i++)
#pragma unroll
        for (int j = 0; j < 8; j++) acc[i][j] = 0.f;

    for (int kk = k0; kk < k0 + (CC * HH) / NKW; kk += 32) {
        __syncthreads();
        {
            const int r = t >> 3, cq = (t & 7) * 16;
            const float* src = Xb + ((size_t)kk + r) * WW + cq;
            float* dst = xs + r * 132 + cq;
#pragma unroll
            for (int j = 0; j < 4; j++)
                *(float4*)(dst + 4 * j) = *(const float4*)(src + 4 * j);
        }
        __syncthreads();
#pragma unroll 8
        for (int k = 0; k < 32; k++) {
            const float* row = xs + k * 132;
            float4 t0 = *(const float4*)(row + ty * 8);
            float4 t1 = *(const float4*)(row + ty * 8 + 4);
            float4 u0 = *(const float4*)(row + tx * 8);
            float4 u1 = *(const float4*)(row + tx * 8 + 4);
            float av[8] = {t0.x, t0.y, t0.z, t0.w, t1.x, t1.y, t1.z, t1.w};
            float bv[8] = {u0.x, u0.y, u0.z, u0.w, u1.x, u1.y, u1.z, u1.w};
#pragma unroll
            for (int i = 0; i < 8; i++)
#pragma unroll
                for (int j = 0; j < 8; j++) acc[i][j] += av[i] * bv[j];
        }
    }
    float* dst = pW + ((size_t)b * NKW + kc) * 16384;
#pragma unroll
    for (int i = 0; i < 8; i++)
#pragma unroll
        for (int j = 0; j < 8; j += 4) {
            float4 v = make_float4(acc[i][j], acc[i][j + 1], acc[i][j + 2], acc[i][j + 3]);
            *(float4*)(dst + (ty * 8 + i) * 128 + tx * 8 + j) = v;
        }
}

__global__ __launch_bounds__(256) void k_redW(const float* __restrict__ pW, float* __restrict__ Tw)
{
    const int b = blockIdx.y;
    const int idx = blockIdx.x * 256 + threadIdx.x;
    const float* p = pW + (size_t)b * NKW * 16384 + idx;
    float acc = 0.f;
#pragma unroll
    for (int k = 0; k < NKW; k++) acc += p[(size_t)k * 16384];
    Tw[(size_t)b * 16384 + idx] = acc;
}

// softmax over w per column v; emits TwT fp16 [v][w]; no fp32 writeback
__global__ __launch_bounds__(1024) void k_softW(const float* __restrict__ Tw, _Float16* __restrict__ twt)
{
    __shared__ float red[32 * 33];
    const int b = blockIdx.x, v0 = blockIdx.y * 32;
    const int t = threadIdx.x;
    const int vc = t & 31, wg = t >> 5;
    const float* S = Tw + (size_t)b * 16384 + v0 + vc;

    float v[4];
    float m = -3.4e38f;
#pragma unroll
    for (int j = 0; j < 4; j++) { v[j] = S[(wg * 4 + j) * 128]; m = fmaxf(m, v[j]); }
    red[wg * 33 + vc] = m;
    __syncthreads();
    for (int st = 16; st > 0; st >>= 1) {
        if (wg < st) red[wg * 33 + vc] = fmaxf(red[wg * 33 + vc], red[(wg + st) * 33 + vc]);
        __syncthreads();
    }
    m = red[vc];
    __syncthreads();
    float sum = 0.f;
#pragma unroll
    for (int j = 0; j < 4; j++) { v[j] = __expf(v[j] - m); sum += v[j]; }
    red[wg * 33 + vc] = sum;
    __syncthreads();
    for (int st = 16; st > 0; st >>= 1) {
        if (wg < st) red[wg * 33 + vc] += red[(wg + st) * 33 + vc];
        __syncthreads();
    }
    const float inv = 1.f / red[vc];
    _Float16* dst = twt + (size_t)b * 16384 + (size_t)(v0 + vc) * 128 + wg * 4;
#pragma unroll
    for (int j = 0; j < 4; j++) dst[j] = (_Float16)(v[j] * inv);
}

// ---------------- gram C partials (fp32 — feeds softmax, keep precision) ----------------
__global__ __launch_bounds__(256) void k_gramC(const float* __restrict__ inp, float* __restrict__ pC)
{
    __shared__ float xt[32 * 68];
    const int b = blockIdx.y, nc = blockIdx.x;
    const int t = threadIdx.x, tx = t & 15, ty = t >> 4;
    const float* ip = inp + (size_t)b * CC * NN;
    const int n0 = nc * (NN / NKC);

    float acc[4][4];
#pragma unroll
    for (int i = 0; i < 4; i++)
#pragma unroll
        for (int j = 0; j < 4; j++) acc[i][j] = 0.f;

    const int scc = t >> 2;
    const int sn  = (t & 3) * 8;

    for (int nt = 0; nt < NN / NKC; nt += 32) {
        __syncthreads();
        {
            const float* src = ip + (size_t)scc * NN + n0 + nt + sn;
            float v[8];
            *(float4*)(v)     = *(const float4*)(src);
            *(float4*)(v + 4) = *(const float4*)(src + 4);
#pragma unroll
            for (int j = 0; j < 8; j++) xt[(sn + j) * 68 + scc] = v[j];
        }
        __syncthreads();
#pragma unroll 8
        for (int nn = 0; nn < 32; nn++) {
            const float4 a4 = *(const float4*)(xt + nn * 68 + ty * 4);
            const float4 e4 = *(const float4*)(xt + nn * 68 + tx * 4);
            const float av[4] = {a4.x, a4.y, a4.z, a4.w};
            const float ev[4] = {e4.x, e4.y, e4.z, e4.w};
#pragma unroll
            for (int i = 0; i < 4; i++)
#pragma unroll
                for (int j = 0; j < 4; j++) acc[i][j] += av[i] * ev[j];
        }
    }
    float* dst = pC + ((size_t)b * NKC + nc) * 4096;
#pragma unroll
    for (int i = 0; i < 4; i++) {
        float4 v = make_float4(acc[i][0], acc[i][1], acc[i][2], acc[i][3]);
        *(float4*)(dst + (ty * 4 + i) * 64 + tx * 4) = v;
    }
}

__global__ __launch_bounds__(256) void k_redC(const float* __restrict__ pC, float* __restrict__ Tc)
{
    const int b = blockIdx.y;
    const int idx = blockIdx.x * 256 + threadIdx.x;
    const float* p = pC + (size_t)b * NKC * 4096 + idx;
    float acc = 0.f;
#pragma unroll
    for (int k = 0; k < NKC; k++) acc += p[(size_t)k * 4096];
    Tc[(size_t)b * 4096 + idx] = acc;
}

// softmax over c per column d; emits TcT fp16 [d][c]; no fp32 writeback
__global__ __launch_bounds__(1024) void k_softC(const float* __restrict__ Tc, _Float16* __restrict__ tct)
{
    __shared__ float red[16 * 65];
    const int b = blockIdx.x;
    const int t = threadIdx.x;
    const int dc = t & 63, cg = t >> 6;
    const float* S = Tc + (size_t)b * 4096 + dc;

    float v[4];
    float m = -3.4e38f;
#pragma unroll
    for (int j = 0; j < 4; j++) { v[j] = S[(cg * 4 + j) * 64]; m = fmaxf(m, v[j]); }
    red[cg * 65 + dc] = m;
    __syncthreads();
    for (int st = 8; st > 0; st >>= 1) {
        if (cg < st) red[cg * 65 + dc] = fmaxf(red[cg * 65 + dc], red[(cg + st) * 65 + dc]);
        __syncthreads();
    }
    m = red[dc];
    __syncthreads();
    float sum = 0.f;
#pragma unroll
    for (int j = 0; j < 4; j++) { v[j] = __expf(v[j] - m); sum += v[j]; }
    red[cg * 65 + dc] = sum;
    __syncthreads();
    for (int st = 8; st > 0; st >>= 1) {
        if (cg < st) red[cg * 65 + dc] += red[(cg + st) * 65 + dc];
        __syncthreads();
    }
    const float inv = 1.f / red[dc];
    _Float16* dst = tct + (size_t)b * 4096 + (size_t)dc * 64 + cg * 4;
#pragma unroll
    for (int j = 0; j < 4; j++) dst[j] = (_Float16)(v[j] * inv);
}

// ---------------- Co via MFMA fp16 (round-12, passed) ----------------
__global__ __launch_bounds__(256) void k_co(
    const float* __restrict__ inp, const _Float16* __restrict__ tct,
    const float* __restrict__ detal, float* __restrict__ s)
{
    __shared__ __align__(16) _Float16 xh[128 * 72];   // [n][c], stride 72
    __shared__ __align__(16) _Float16 tl[64 * 72];    // [d][c], stride 72
    const int b  = blockIdx.y;
    const int n0 = blockIdx.x * 128;
    const int t  = threadIdx.x;
    const int l  = t & 63, wv = t >> 6;
    const int lr = l & 15, kg = (l >> 4) * 8;

    {
        const int nn = t & 127, ch = t >> 7;
        const float* src = inp + ((size_t)b * CC + ch * 32) * NN + n0 + nn;
#pragma unroll
        for (int k2 = 0; k2 < 4; ++k2) {
            float f[8];
#pragma unroll
            for (int j = 0; j < 8; ++j) f[j] = src[(size_t)(k2 * 8 + j) * NN];
            f16x8 h;
#pragma unroll
            for (int j = 0; j < 8; ++j) h[j] = (_Float16)f[j];
            *(f16x8*)(xh + nn * 72 + ch * 32 + k2 * 8) = h;
        }
    }
    {
        const int d = t >> 2, cq = (t & 3) * 16;
        const _Float16* src = tct + (size_t)b * 4096 + d * 64 + cq;
        *(uint4*)(tl + d * 72 + cq)     = *(const uint4*)(src);
        *(uint4*)(tl + d * 72 + cq + 8) = *(const uint4*)(src + 8);
    }
    __syncthreads();

    f32x4 acc[2][4];
#pragma unroll
    for (int mt = 0; mt < 2; mt++)
#pragma unroll
        for (int nt = 0; nt < 4; nt++) acc[mt][nt] = (f32x4){0.f, 0.f, 0.f, 0.f};

#pragma unroll
    for (int kc = 0; kc < 2; ++kc) {
        f16x8 bf[4];
#pragma unroll
        for (int nt = 0; nt < 4; ++nt)
            bf[nt] = *(const f16x8*)(tl + (nt * 16 + lr) * 72 + kc * 32 + kg);
#pragma unroll
        for (int mt = 0; mt < 2; ++mt) {
            const f16x8 af = *(const f16x8*)(xh + (wv * 32 + mt * 16 + lr) * 72 + kc * 32 + kg);
#pragma unroll
            for (int nt = 0; nt < 4; ++nt)
                acc[mt][nt] = __builtin_amdgcn_mfma_f32_16x16x32_f16(af, bf[nt], acc[mt][nt], 0, 0, 0);
        }
    }

    const float scl = detal[0];
    float* sb = s + (size_t)b * CC * NN;
#pragma unroll
    for (int mt = 0; mt < 2; ++mt)
#pragma unroll
        for (int nt = 0; nt < 4; ++nt) {
            const int d = nt * 16 + lr;
#pragma unroll
            for (int r = 0; r < 4; ++r) {
                const int n = n0 + wv * 32 + mt * 16 + (l >> 4) * 4 + r;
                sb[(size_t)n * 64 + d] = scl * acc[mt][nt][r];
            }
        }
}

// ---------------- Wo (==Ho) via MFMA fp16 (round-12, passed) ----------------
__global__ __launch_bounds__(256) void k_wo(
    const float* __restrict__ inp, const _Float16* __restrict__ twt,
    const float* __restrict__ detal, float* __restrict__ s)
{
    __shared__ __align__(16) _Float16 xh[64 * 136];    // [h][w], stride 136
    __shared__ __align__(16) _Float16 tl[128 * 136];   // [v][w], stride 136
    const int b = blockIdx.z, hc = blockIdx.y, c = blockIdx.x;
    const int t = threadIdx.x;
    const int l = t & 63, wv = t >> 6;
    const int lr = l & 15, kg = (l >> 4) * 8;
    const int h0 = hc * 64;

    const float* ip = inp + ((size_t)b * CC + c) * NN + (size_t)h0 * WW;

    {
        const int h = t >> 2, wq = (t & 3) * 32;
        const float* src = ip + (size_t)h * WW + wq;
#pragma unroll
        for (int k2 = 0; k2 < 4; ++k2) {
            const float4 v0 = *(const float4*)(src + k2 * 8);
            const float4 v1 = *(const float4*)(src + k2 * 8 + 4);
            f16x8 h8;
            h8[0] = (_Float16)v0.x; h8[1] = (_Float16)v0.y;
            h8[2] = (_Float16)v0.z; h8[3] = (_Float16)v0.w;
            h8[4] = (_Float16)v1.x; h8[5] = (_Float16)v1.y;
            h8[6] = (_Float16)v1.z; h8[7] = (_Float16)v1.w;
            *(f16x8*)(xh + h * 136 + wq + k2 * 8) = h8;
        }
    }
    {
        const int v = t >> 1, wh2 = (t & 1) * 64;
        const _Float16* src = twt + (size_t)b * 16384 + (size_t)v * 128 + wh2;
        uint4* dst = (uint4*)(tl + v * 136 + wh2);
#pragma unroll
        for (int k = 0; k < 8; ++k) dst[k] = *(const uint4*)(src + 8 * k);
    }
    __syncthreads();

    f32x4 acc[8];
#pragma unroll
    for (int nt = 0; nt < 8; nt++) acc[nt] = (f32x4){0.f, 0.f, 0.f, 0.f};

#pragma unroll
    for (int kc = 0; kc < 4; ++kc) {
        const f16x8 af = *(const f16x8*)(xh + (wv * 16 + lr) * 136 + kc * 32 + kg);
#pragma unroll
        for (int nt = 0; nt < 8; ++nt) {
            const f16x8 bf = *(const f16x8*)(tl + (nt * 16 + lr) * 136 + kc * 32 + kg);
            acc[nt] = __builtin_amdgcn_mfma_f32_16x16x32_f16(af, bf, acc[nt], 0, 0, 0);
        }
    }

    const float sc2 = 2.0f * detal[0];
    float* sp = s + ((size_t)b * CC + c) * NN + (size_t)h0 * WW;
#pragma unroll
    for (int nt = 0; nt < 8; ++nt) {
        const int v = nt * 16 + lr;
#pragma unroll
        for (int r = 0; r < 4; ++r) {
            const int h = wv * 16 + (l >> 4) * 4 + r;
            float* p = sp + (size_t)h * WW + v;
            *p = *p + sc2 * acc[nt][r];
        }
    }
}

// ---------------- outconv via MFMA fp16: out = w_out·s + b_out + x ----------------
// grid (NN/64, NB), block 256 (4 waves). Tile 256o x 64n, K=64 staged ONCE (1 barrier).
// s staged TRANSPOSED fp16 [n][72] via per-lane scalar reads (coalesced along n) so
// B-fragments are single ds_read_b128 (was 8x ds_read_u16 each). W [o][72] in LDS once.
__global__ __launch_bounds__(256) void k_outconv(
    const float* __restrict__ s, const _Float16* __restrict__ woh,
    const float* __restrict__ b_out, const float* __restrict__ x,
    float* __restrict__ outp)
{
    __shared__ __align__(16) _Float16 wo[256 * 72];   // [o][c]
    __shared__ __align__(16) _Float16 sh[64 * 72];    // [n][c], stride 72
    const int b  = blockIdx.y;
    const int n0 = blockIdx.x * 64;
    const int t  = threadIdx.x;
    const int l  = t & 63, wv = t >> 6;
    const int lr = l & 15, kg = (l >> 4) * 8;

    {   // load W once: 256 rows x 64 halves
        const uint4* src = (const uint4*)(woh + t * 64);
        uint4* dst = (uint4*)(wo + t * 72);
#pragma unroll
        for (int k = 0; k < 8; k++) dst[k] = src[k];
    }
    {   // stage s^T: thread owns n=t&63, c-range (t>>6)*16..+15
        const int nn = t & 63, ch = t >> 6;
        const float* src = s + ((size_t)b * CC + ch * 16) * NN + n0 + nn;
#pragma unroll
        for (int k2 = 0; k2 < 2; ++k2) {
            float f[8];
#pragma unroll
            for (int j = 0; j < 8; ++j) f[j] = src[(size_t)(k2 * 8 + j) * NN];
            f16x8 h;
#pragma unroll
            for (int j = 0; j < 8; ++j) h[j] = (_Float16)f[j];
            *(f16x8*)(sh + nn * 72 + ch * 16 + k2 * 8) = h;
        }
    }
    __syncthreads();

    f32x4 acc[4][4];
#pragma unroll
    for (int mt = 0; mt < 4; mt++)
#pragma unroll
        for (int nt = 0; nt < 4; nt++) acc[mt][nt] = (f32x4){0.f, 0.f, 0.f, 0.f};

#pragma unroll
    for (int kc = 0; kc < 2; ++kc) {
        f16x8 bf[4];
#pragma unroll
        for (int nt = 0; nt < 4; ++nt)
            bf[nt] = *(const f16x8*)(sh + (nt * 16 + lr) * 72 + kc * 32 + kg);
#pragma unroll
        for (int mt = 0; mt < 4; ++mt) {
            const f16x8 af = *(const f16x8*)(wo + (wv * 64 + mt * 16 + lr) * 72 + kc * 32 + kg);
#pragma unroll
            for (int nt = 0; nt < 4; ++nt)
                acc[mt][nt] = __builtin_amdgcn_mfma_f32_16x16x32_f16(af, bf[nt], acc[mt][nt], 0, 0, 0);
        }
    }

#pragma unroll
    for (int mt = 0; mt < 4; ++mt)
#pragma unroll
        for (int nt = 0; nt < 4; ++nt) {
            const int n = n0 + nt * 16 + lr;
#pragma unroll
            for (int r = 0; r < 4; ++r) {
                const int o = wv * 64 + mt * 16 + (l >> 4) * 4 + r;
                const size_t off = ((size_t)b * IC + o) * NN + n;
                outp[off] = (float)acc[mt][nt][r] + b_out[o] + x[off];
            }
        }
}

extern "C" void kernel_launch(void* const* d_in, const int* in_sizes, int n_in,
                              void* d_out, int out_size, void* d_ws, size_t ws_size,
                              hipStream_t stream)
{
    const float* x     = (const float*)d_in[0];
    const float* w_in  = (const float*)d_in[1];
    const float* b_in  = (const float*)d_in[2];
    const float* w_out = (const float*)d_in[3];
    const float* b_out = (const float*)d_in[4];
    const float* detal = (const float*)d_in[5];
    float* out = (float*)d_out;

    float* ws   = (float*)d_ws;
    float* inp  = ws + OFF_INP;
    float* s    = ws + OFF_S;
    float* pW   = ws + OFF_S;      // aliased with s (pW dead before k_co writes s)
    float* pC   = ws + OFF_PC;
    float* Tw   = ws + OFF_TW;
    float* Tc   = ws + OFF_TC;
    _Float16* wh  = (_Float16*)(ws + OFF_WT);
    _Float16* woh = (_Float16*)(ws + OFF_WOT);
    _Float16* twt = (_Float16*)(ws + OFF_TWT);
    _Float16* tct = (_Float16*)(ws + OFF_TCT);

    k_wt     <<<dim3(128),              256, 0, stream>>>(w_in, w_out, wh, woh);
    k_inconv <<<dim3(NN / 128, NB),     256, 0, stream>>>(x, wh, b_in, inp);
    k_gramW  <<<dim3(NKW, NB),          256, 0, stream>>>(inp, pW);
    k_redW   <<<dim3(64, NB),           256, 0, stream>>>(pW, Tw);
    k_softW  <<<dim3(NB, 4),           1024, 0, stream>>>(Tw, twt);
    k_gramC  <<<dim3(NKC, NB),          256, 0, stream>>>(inp, pC);
    k_redC   <<<dim3(16, NB),           256, 0, stream>>>(pC, Tc);
    k_softC  <<<dim3(NB),              1024, 0, stream>>>(Tc, tct);
    k_co     <<<dim3(NN / 128, NB),     256, 0, stream>>>(inp, tct, detal, s);
    k_wo     <<<dim3(CC, 2, NB),        256, 0, stream>>>(inp, twt, detal, s);
    k_outconv<<<dim3(NN / 64, NB),      256, 0, stream>>>(s, woh, b_out, x, out);
}

// Round 14
// 364.804 us; speedup vs baseline: 1.2205x; 1.1284x over previous
//
#include <hip/hip_runtime.h>
#include <math.h>

#define NB 8
#define IC 256
#define CC 64
#define HH 128
#define WW 128
#define NN (HH*WW)      // 16384
#define NKW 32          // k-chunks for gramW (8192/32 = 256 k per chunk)
#define NKC 32          // n-chunks for gramC (16384/32 = 512 n per chunk)

typedef _Float16 f16x8 __attribute__((ext_vector_type(8)));
typedef float f32x4 __attribute__((ext_vector_type(4)));

// ---------------- workspace layout (floats) ----------------
static constexpr size_t SZ_INP  = (size_t)NB * CC * NN;            // 8,388,608
static constexpr size_t OFF_INP = 0;
static constexpr size_t OFF_S   = OFF_INP + SZ_INP;                // s AND pW (aliased; pW = NB*32*16384 = 4.2M < 8.4M)
static constexpr size_t OFF_PC  = OFF_S + SZ_INP;                  // pC: NB*32*4096 = 1.05M
static constexpr size_t OFF_TW  = OFF_PC + (size_t)NB * NKC * 4096;
static constexpr size_t OFF_TC  = OFF_TW + (size_t)NB * 16384;
static constexpr size_t OFF_WT  = OFF_TC + (size_t)NB * 4096;      // w_in fp16 [64 o][256 i]
static constexpr size_t OFF_WOT = OFF_WT + 16384;                  // w_out fp16 [256 o][64 c]
static constexpr size_t OFF_TWT = OFF_WOT + 16384;                 // TwT fp16 [b][v 128][w 128]
static constexpr size_t OFF_TCT = OFF_TWT + 65536;                 // TcT fp16 [b][d 64][c 64]

// ---------------- weight fp16 casts ----------------
__global__ __launch_bounds__(256) void k_wt(
    const float* __restrict__ w_in, const float* __restrict__ w_out,
    _Float16* __restrict__ wh, _Float16* __restrict__ woh)
{
    const int idx = blockIdx.x * 256 + threadIdx.x;   // 0..32767
    if (idx < 16384) wh[idx] = (_Float16)w_in[idx];           // [o][i]
    else             woh[idx - 16384] = (_Float16)w_out[idx - 16384];  // [o][c]
}

// ---------------- inconv via MFMA fp16 (round-13, passed) ----------------
__global__ __launch_bounds__(256) void k_inconv(
    const float* __restrict__ x, const _Float16* __restrict__ wh,
    const float* __restrict__ b_in, float* __restrict__ inp)
{
    __shared__ __align__(16) _Float16 wl[64 * 264];   // [o][i]
    __shared__ __align__(16) _Float16 xh[128 * 72];   // [n][i-chunk 64], stride 72
    const int b  = blockIdx.y;
    const int n0 = blockIdx.x * 128;
    const int t  = threadIdx.x;
    const int l  = t & 63, wv = t >> 6;
    const int lr = l & 15, kg = (l >> 4) * 8;

    {   // load W once: 64 rows x 256 halves
        const int r = t >> 2, c = (t & 3) * 64;
        const uint4* src = (const uint4*)(wh + r * 256 + c);
        uint4* dst = (uint4*)(wl + r * 264 + c);
#pragma unroll
        for (int k = 0; k < 8; k++) dst[k] = src[k];
    }

    f32x4 acc[4][2];
#pragma unroll
    for (int mt = 0; mt < 4; mt++)
#pragma unroll
        for (int nt = 0; nt < 2; nt++) acc[mt][nt] = (f32x4){0.f, 0.f, 0.f, 0.f};

    for (int kc = 0; kc < 4; ++kc) {
        __syncthreads();
        {   // stage x^T chunk: thread owns n=t&127, i-range (t>>7)*32..+31
            const int nn = t & 127, ch = t >> 7;
            const float* src = x + ((size_t)b * IC + kc * 64 + ch * 32) * NN + n0 + nn;
#pragma unroll
            for (int k2 = 0; k2 < 4; ++k2) {
                float f[8];
#pragma unroll
                for (int j = 0; j < 8; ++j) f[j] = src[(size_t)(k2 * 8 + j) * NN];
                f16x8 h;
#pragma unroll
                for (int j = 0; j < 8; ++j) h[j] = (_Float16)f[j];
                *(f16x8*)(xh + nn * 72 + ch * 32 + k2 * 8) = h;
            }
        }
        __syncthreads();

#pragma unroll
        for (int kk = 0; kk < 2; ++kk) {
            f16x8 bf[2];
#pragma unroll
            for (int nt = 0; nt < 2; ++nt)
                bf[nt] = *(const f16x8*)(xh + (wv * 32 + nt * 16 + lr) * 72 + kk * 32 + kg);
#pragma unroll
            for (int mt = 0; mt < 4; ++mt) {
                const f16x8 af = *(const f16x8*)(wl + (mt * 16 + lr) * 264 + kc * 64 + kk * 32 + kg);
                acc[mt][0] = __builtin_amdgcn_mfma_f32_16x16x32_f16(af, bf[0], acc[mt][0], 0, 0, 0);
                acc[mt][1] = __builtin_amdgcn_mfma_f32_16x16x32_f16(af, bf[1], acc[mt][1], 0, 0, 0);
            }
        }
    }

#pragma unroll
    for (int mt = 0; mt < 4; ++mt)
#pragma unroll
        for (int nt = 0; nt < 2; ++nt) {
            const int n = n0 + wv * 32 + nt * 16 + lr;
#pragma unroll
            for (int r = 0; r < 4; ++r) {
                const int o = mt * 16 + (l >> 4) * 4 + r;
                inp[((size_t)b * CC + o) * NN + n] = (float)acc[mt][nt][r] + b_in[o];
            }
        }
}

// ---------------- gram W via split-fp16 MFMA: Tw = Xw^T Xw over [8192 k][128 w] view ----------------
// a = hi + lo (lo = a - fp16(a)); G = hi·hi + hi·lo + lo·hi (lo·lo ~2^-22, dropped) ->
// fp32-quality logits for the downstream softmax. A and B frags share one transposed
// [w][k] tile (k-contiguous b128). grid (32, NB); K-chunk 256 in 4 sub-chunks of 64.
__global__ __launch_bounds__(256) void k_gramW(const float* __restrict__ inp, float* __restrict__ pW)
{
    __shared__ __align__(16) _Float16 xhi[128 * 72];   // [w][k64], stride 72
    __shared__ __align__(16) _Float16 xlo[128 * 72];
    const int b = blockIdx.y, kc = blockIdx.x;
    const int t = threadIdx.x;
    const int l = t & 63, wv = t >> 6;
    const int lr = l & 15, kg = (l >> 4) * 8;
    const float* inpb = inp + (size_t)b * CC * NN;
    const int k0 = kc * 256;

    f32x4 acc[2][8];
#pragma unroll
    for (int mt = 0; mt < 2; mt++)
#pragma unroll
        for (int nt = 0; nt < 8; nt++) acc[mt][nt] = (f32x4){0.f, 0.f, 0.f, 0.f};

    for (int sub = 0; sub < 4; ++sub) {
        __syncthreads();
        {   // stage transposed hi/lo: thread owns w=t&127, k-half (t>>7)*32
            const int w = t & 127, kh = (t >> 7) * 32;
            const float* src = inpb + (size_t)(k0 + sub * 64 + kh) * 128 + w;
#pragma unroll
            for (int g = 0; g < 4; ++g) {
                float f[8];
#pragma unroll
                for (int j = 0; j < 8; ++j) f[j] = src[(size_t)(g * 8 + j) * 128];
                f16x8 hi, lo;
#pragma unroll
                for (int j = 0; j < 8; ++j) {
                    hi[j] = (_Float16)f[j];
                    lo[j] = (_Float16)(f[j] - (float)hi[j]);
                }
                *(f16x8*)(xhi + w * 72 + kh + g * 8) = hi;
                *(f16x8*)(xlo + w * 72 + kh + g * 8) = lo;
            }
        }
        __syncthreads();

#pragma unroll
        for (int kk = 0; kk < 2; ++kk) {
            f16x8 ah[2], al[2];
#pragma unroll
            for (int mt = 0; mt < 2; ++mt) {
                ah[mt] = *(const f16x8*)(xhi + (wv * 32 + mt * 16 + lr) * 72 + kk * 32 + kg);
                al[mt] = *(const f16x8*)(xlo + (wv * 32 + mt * 16 + lr) * 72 + kk * 32 + kg);
            }
#pragma unroll
            for (int nt = 0; nt < 8; ++nt) {
                const f16x8 bh = *(const f16x8*)(xhi + (nt * 16 + lr) * 72 + kk * 32 + kg);
                const f16x8 bl = *(const f16x8*)(xlo + (nt * 16 + lr) * 72 + kk * 32 + kg);
#pragma unroll
                for (int mt = 0; mt < 2; ++mt) {
                    acc[mt][nt] = __builtin_amdgcn_mfma_f32_16x16x32_f16(ah[mt], bh, acc[mt][nt], 0, 0, 0);
                    acc[mt][nt] = __builtin_amdgcn_mfma_f32_16x16x32_f16(ah[mt], bl, acc[mt][nt], 0, 0, 0);
                    acc[mt][nt] = __builtin_amdgcn_mfma_f32_16x16x32_f16(al[mt], bh, acc[mt][nt], 0, 0, 0);
                }
            }
        }
    }

    float* dst = pW + ((size_t)b * NKW + kc) * 16384;
#pragma unroll
    for (int mt = 0; mt < 2; ++mt)
#pragma unroll
        for (int nt = 0; nt < 8; ++nt) {
            const int v = nt * 16 + lr;
#pragma unroll
            for (int r = 0; r < 4; ++r) {
                const int w = wv * 32 + mt * 16 + (l >> 4) * 4 + r;
                dst[(size_t)w * 128 + v] = acc[mt][nt][r];
            }
        }
}

__global__ __launch_bounds__(256) void k_redW(const float* __restrict__ pW, float* __restrict__ Tw)
{
    const int b = blockIdx.y;
    const int idx = blockIdx.x * 256 + threadIdx.x;
    const float* p = pW + (size_t)b * NKW * 16384 + idx;
    float acc = 0.f;
#pragma unroll
    for (int k = 0; k < NKW; k++) acc += p[(size_t)k * 16384];
    Tw[(size_t)b * 16384 + idx] = acc;
}

// softmax over w per column v; emits TwT fp16 [v][w]; no fp32 writeback
__global__ __launch_bounds__(1024) void k_softW(const float* __restrict__ Tw, _Float16* __restrict__ twt)
{
    __shared__ float red[32 * 33];
    const int b = blockIdx.x, v0 = blockIdx.y * 32;
    const int t = threadIdx.x;
    const int vc = t & 31, wg = t >> 5;
    const float* S = Tw + (size_t)b * 16384 + v0 + vc;

    float v[4];
    float m = -3.4e38f;
#pragma unroll
    for (int j = 0; j < 4; j++) { v[j] = S[(wg * 4 + j) * 128]; m = fmaxf(m, v[j]); }
    red[wg * 33 + vc] = m;
    __syncthreads();
    for (int st = 16; st > 0; st >>= 1) {
        if (wg < st) red[wg * 33 + vc] = fmaxf(red[wg * 33 + vc], red[(wg + st) * 33 + vc]);
        __syncthreads();
    }
    m = red[vc];
    __syncthreads();
    float sum = 0.f;
#pragma unroll
    for (int j = 0; j < 4; j++) { v[j] = __expf(v[j] - m); sum += v[j]; }
    red[wg * 33 + vc] = sum;
    __syncthreads();
    for (int st = 16; st > 0; st >>= 1) {
        if (wg < st) red[wg * 33 + vc] += red[(wg + st) * 33 + vc];
        __syncthreads();
    }
    const float inv = 1.f / red[vc];
    _Float16* dst = twt + (size_t)b * 16384 + (size_t)(v0 + vc) * 128 + wg * 4;
#pragma unroll
    for (int j = 0; j < 4; j++) dst[j] = (_Float16)(v[j] * inv);
}

// ---------------- gram C via split-fp16 MFMA: Tc[c,d] = sum_n inp[c,n] inp[d,n] ----------------
// Native [c][n] layout is already k-contiguous for both frags — no transpose.
// grid (32, NB); n-chunk 512 in 2 sub-chunks of 256.
__global__ __launch_bounds__(256) void k_gramC(const float* __restrict__ inp, float* __restrict__ pC)
{
    __shared__ __align__(16) _Float16 xhi[64 * 264];   // [c][n256], stride 264
    __shared__ __align__(16) _Float16 xlo[64 * 264];
    const int b = blockIdx.y, nc = blockIdx.x;
    const int t = threadIdx.x;
    const int l = t & 63, wv = t >> 6;
    const int lr = l & 15, kg = (l >> 4) * 8;
    const float* inpb = inp + (size_t)b * CC * NN;
    const int n0 = nc * 512;

    f32x4 acc[4];
#pragma unroll
    for (int nt = 0; nt < 4; nt++) acc[nt] = (f32x4){0.f, 0.f, 0.f, 0.f};

    for (int sub = 0; sub < 2; ++sub) {
        __syncthreads();
        {   // stage hi/lo: thread owns c=t>>2, n-off (t&3)*64, 64 floats
            const int c = t >> 2, nq = (t & 3) * 64;
            const float* src = inpb + (size_t)c * NN + n0 + sub * 256 + nq;
#pragma unroll
            for (int g = 0; g < 8; ++g) {
                const float4 v0 = *(const float4*)(src + g * 8);
                const float4 v1 = *(const float4*)(src + g * 8 + 4);
                float f[8] = {v0.x, v0.y, v0.z, v0.w, v1.x, v1.y, v1.z, v1.w};
                f16x8 hi, lo;
#pragma unroll
                for (int j = 0; j < 8; ++j) {
                    hi[j] = (_Float16)f[j];
                    lo[j] = (_Float16)(f[j] - (float)hi[j]);
                }
                *(f16x8*)(xhi + c * 264 + nq + g * 8) = hi;
                *(f16x8*)(xlo + c * 264 + nq + g * 8) = lo;
            }
        }
        __syncthreads();

#pragma unroll
        for (int kk = 0; kk < 8; ++kk) {
            const f16x8 ah = *(const f16x8*)(xhi + (wv * 16 + lr) * 264 + kk * 32 + kg);
            const f16x8 al = *(const f16x8*)(xlo + (wv * 16 + lr) * 264 + kk * 32 + kg);
#pragma unroll
            for (int nt = 0; nt < 4; ++nt) {
                const f16x8 bh = *(const f16x8*)(xhi + (nt * 16 + lr) * 264 + kk * 32 + kg);
                const f16x8 bl = *(const f16x8*)(xlo + (nt * 16 + lr) * 264 + kk * 32 + kg);
                acc[nt] = __builtin_amdgcn_mfma_f32_16x16x32_f16(ah, bh, acc[nt], 0, 0, 0);
                acc[nt] = __builtin_amdgcn_mfma_f32_16x16x32_f16(ah, bl, acc[nt], 0, 0, 0);
                acc[nt] = __builtin_amdgcn_mfma_f32_16x16x32_f16(al, bh, acc[nt], 0, 0, 0);
            }
        }
    }

    float* dst = pC + ((size_t)b * NKC + nc) * 4096;
#pragma unroll
    for (int nt = 0; nt < 4; ++nt) {
        const int d = nt * 16 + lr;
#pragma unroll
        for (int r = 0; r < 4; ++r) {
            const int c = wv * 16 + (l >> 4) * 4 + r;
            dst[(size_t)c * 64 + d] = acc[nt][r];
        }
    }
}

__global__ __launch_bounds__(256) void k_redC(const float* __restrict__ pC, float* __restrict__ Tc)
{
    const int b = blockIdx.y;
    const int idx = blockIdx.x * 256 + threadIdx.x;
    const float* p = pC + (size_t)b * NKC * 4096 + idx;
    float acc = 0.f;
#pragma unroll
    for (int k = 0; k < NKC; k++) acc += p[(size_t)k * 4096];
    Tc[(size_t)b * 4096 + idx] = acc;
}

// softmax over c per column d; emits TcT fp16 [d][c]; no fp32 writeback
__global__ __launch_bounds__(1024) void k_softC(const float* __restrict__ Tc, _Float16* __restrict__ tct)
{
    __shared__ float red[16 * 65];
    const int b = blockIdx.x;
    const int t = threadIdx.x;
    const int dc = t & 63, cg = t >> 6;
    const float* S = Tc + (size_t)b * 4096 + dc;

    float v[4];
    float m = -3.4e38f;
#pragma unroll
    for (int j = 0; j < 4; j++) { v[j] = S[(cg * 4 + j) * 64]; m = fmaxf(m, v[j]); }
    red[cg * 65 + dc] = m;
    __syncthreads();
    for (int st = 8; st > 0; st >>= 1) {
        if (cg < st) red[cg * 65 + dc] = fmaxf(red[cg * 65 + dc], red[(cg + st) * 65 + dc]);
        __syncthreads();
    }
    m = red[dc];
    __syncthreads();
    float sum = 0.f;
#pragma unroll
    for (int j = 0; j < 4; j++) { v[j] = __expf(v[j] - m); sum += v[j]; }
    red[cg * 65 + dc] = sum;
    __syncthreads();
    for (int st = 8; st > 0; st >>= 1) {
        if (cg < st) red[cg * 65 + dc] += red[(cg + st) * 65 + dc];
        __syncthreads();
    }
    const float inv = 1.f / red[dc];
    _Float16* dst = tct + (size_t)b * 4096 + (size_t)dc * 64 + cg * 4;
#pragma unroll
    for (int j = 0; j < 4; j++) dst[j] = (_Float16)(v[j] * inv);
}

// ---------------- Co via MFMA fp16 (round-12, passed) ----------------
__global__ __launch_bounds__(256) void k_co(
    const float* __restrict__ inp, const _Float16* __restrict__ tct,
    const float* __restrict__ detal, float* __restrict__ s)
{
    __shared__ __align__(16) _Float16 xh[128 * 72];   // [n][c], stride 72
    __shared__ __align__(16) _Float16 tl[64 * 72];    // [d][c], stride 72
    const int b  = blockIdx.y;
    const int n0 = blockIdx.x * 128;
    const int t  = threadIdx.x;
    const int l  = t & 63, wv = t >> 6;
    const int lr = l & 15, kg = (l >> 4) * 8;

    {
        const int nn = t & 127, ch = t >> 7;
        const float* src = inp + ((size_t)b * CC + ch * 32) * NN + n0 + nn;
#pragma unroll
        for (int k2 = 0; k2 < 4; ++k2) {
            float f[8];
#pragma unroll
            for (int j = 0; j < 8; ++j) f[j] = src[(size_t)(k2 * 8 + j) * NN];
            f16x8 h;
#pragma unroll
            for (int j = 0; j < 8; ++j) h[j] = (_Float16)f[j];
            *(f16x8*)(xh + nn * 72 + ch * 32 + k2 * 8) = h;
        }
    }
    {
        const int d = t >> 2, cq = (t & 3) * 16;
        const _Float16* src = tct + (size_t)b * 4096 + d * 64 + cq;
        *(uint4*)(tl + d * 72 + cq)     = *(const uint4*)(src);
        *(uint4*)(tl + d * 72 + cq + 8) = *(const uint4*)(src + 8);
    }
    __syncthreads();

    f32x4 acc[2][4];
#pragma unroll
    for (int mt = 0; mt < 2; mt++)
#pragma unroll
        for (int nt = 0; nt < 4; nt++) acc[mt][nt] = (f32x4){0.f, 0.f, 0.f, 0.f};

#pragma unroll
    for (int kc = 0; kc < 2; ++kc) {
        f16x8 bf[4];
#pragma unroll
        for (int nt = 0; nt < 4; ++nt)
            bf[nt] = *(const f16x8*)(tl + (nt * 16 + lr) * 72 + kc * 32 + kg);
#pragma unroll
        for (int mt = 0; mt < 2; ++mt) {
            const f16x8 af = *(const f16x8*)(xh + (wv * 32 + mt * 16 + lr) * 72 + kc * 32 + kg);
#pragma unroll
            for (int nt = 0; nt < 4; ++nt)
                acc[mt][nt] = __builtin_amdgcn_mfma_f32_16x16x32_f16(af, bf[nt], acc[mt][nt], 0, 0, 0);
        }
    }

    const float scl = detal[0];
    float* sb = s + (size_t)b * CC * NN;
#pragma unroll
    for (int mt = 0; mt < 2; ++mt)
#pragma unroll
        for (int nt = 0; nt < 4; ++nt) {
            const int d = nt * 16 + lr;
#pragma unroll
            for (int r = 0; r < 4; ++r) {
                const int n = n0 + wv * 32 + mt * 16 + (l >> 4) * 4 + r;
                sb[(size_t)n * 64 + d] = scl * acc[mt][nt][r];
            }
        }
}

// ---------------- Wo (==Ho) via MFMA fp16 (round-12, passed) ----------------
__global__ __launch_bounds__(256) void k_wo(
    const float* __restrict__ inp, const _Float16* __restrict__ twt,
    const float* __restrict__ detal, float* __restrict__ s)
{
    __shared__ __align__(16) _Float16 xh[64 * 136];    // [h][w], stride 136
    __shared__ __align__(16) _Float16 tl[128 * 136];   // [v][w], stride 136
    const int b = blockIdx.z, hc = blockIdx.y, c = blockIdx.x;
    const int t = threadIdx.x;
    const int l = t & 63, wv = t >> 6;
    const int lr = l & 15, kg = (l >> 4) * 8;
    const int h0 = hc * 64;

    const float* ip = inp + ((size_t)b * CC + c) * NN + (size_t)h0 * WW;

    {
        const int h = t >> 2, wq = (t & 3) * 32;
        const float* src = ip + (size_t)h * WW + wq;
#pragma unroll
        for (int k2 = 0; k2 < 4; ++k2) {
            const float4 v0 = *(const float4*)(src + k2 * 8);
            const float4 v1 = *(const float4*)(src + k2 * 8 + 4);
            f16x8 h8;
            h8[0] = (_Float16)v0.x; h8[1] = (_Float16)v0.y;
            h8[2] = (_Float16)v0.z; h8[3] = (_Float16)v0.w;
            h8[4] = (_Float16)v1.x; h8[5] = (_Float16)v1.y;
            h8[6] = (_Float16)v1.z; h8[7] = (_Float16)v1.w;
            *(f16x8*)(xh + h * 136 + wq + k2 * 8) = h8;
        }
    }
    {
        const int v = t >> 1, wh2 = (t & 1) * 64;
        const _Float16* src = twt + (size_t)b * 16384 + (size_t)v * 128 + wh2;
        uint4* dst = (uint4*)(tl + v * 136 + wh2);
#pragma unroll
        for (int k = 0; k < 8; ++k) dst[k] = *(const uint4*)(src + 8 * k);
    }
    __syncthreads();

    f32x4 acc[8];
#pragma unroll
    for (int nt = 0; nt < 8; nt++) acc[nt] = (f32x4){0.f, 0.f, 0.f, 0.f};

#pragma unroll
    for (int kc = 0; kc < 4; ++kc) {
        const f16x8 af = *(const f16x8*)(xh + (wv * 16 + lr) * 136 + kc * 32 + kg);
#pragma unroll
        for (int nt = 0; nt < 8; ++nt) {
            const f16x8 bf = *(const f16x8*)(tl + (nt * 16 + lr) * 136 + kc * 32 + kg);
            acc[nt] = __builtin_amdgcn_mfma_f32_16x16x32_f16(af, bf, acc[nt], 0, 0, 0);
        }
    }

    const float sc2 = 2.0f * detal[0];
    float* sp = s + ((size_t)b * CC + c) * NN + (size_t)h0 * WW;
#pragma unroll
    for (int nt = 0; nt < 8; ++nt) {
        const int v = nt * 16 + lr;
#pragma unroll
        for (int r = 0; r < 4; ++r) {
            const int h = wv * 16 + (l >> 4) * 4 + r;
            float* p = sp + (size_t)h * WW + v;
            *p = *p + sc2 * acc[nt][r];
        }
    }
}

// ---------------- outconv via MFMA fp16 (round-13, passed) ----------------
__global__ __launch_bounds__(256) void k_outconv(
    const float* __restrict__ s, const _Float16* __restrict__ woh,
    const float* __restrict__ b_out, const float* __restrict__ x,
    float* __restrict__ outp)
{
    __shared__ __align__(16) _Float16 wo[256 * 72];   // [o][c]
    __shared__ __align__(16) _Float16 sh[64 * 72];    // [n][c], stride 72
    const int b  = blockIdx.y;
    const int n0 = blockIdx.x * 64;
    const int t  = threadIdx.x;
    const int l  = t & 63, wv = t >> 6;
    const int lr = l & 15, kg = (l >> 4) * 8;

    {   // load W once: 256 rows x 64 halves
        const uint4* src = (const uint4*)(woh + t * 64);
        uint4* dst = (uint4*)(wo + t * 72);
#pragma unroll
        for (int k = 0; k < 8; k++) dst[k] = src[k];
    }
    {   // stage s^T: thread owns n=t&63, c-range (t>>6)*16..+15
        const int nn = t & 63, ch = t >> 6;
        const float* src = s + ((size_t)b * CC + ch * 16) * NN + n0 + nn;
#pragma unroll
        for (int k2 = 0; k2 < 2; ++k2) {
            float f[8];
#pragma unroll
            for (int j = 0; j < 8; ++j) f[j] = src[(size_t)(k2 * 8 + j) * NN];
            f16x8 h;
#pragma unroll
            for (int j = 0; j < 8; ++j) h[j] = (_Float16)f[j];
            *(f16x8*)(sh + nn * 72 + ch * 16 + k2 * 8) = h;
        }
    }
    __syncthreads();

    f32x4 acc[4][4];
#pragma unroll
    for (int mt = 0; mt < 4; mt++)
#pragma unroll
        for (int nt = 0; nt < 4; nt++) acc[mt][nt] = (f32x4){0.f, 0.f, 0.f, 0.f};

#pragma unroll
    for (int kc = 0; kc < 2; ++kc) {
        f16x8 bf[4];
#pragma unroll
        for (int nt = 0; nt < 4; ++nt)
            bf[nt] = *(const f16x8*)(sh + (nt * 16 + lr) * 72 + kc * 32 + kg);
#pragma unroll
        for (int mt = 0; mt < 4; ++mt) {
            const f16x8 af = *(const f16x8*)(wo + (wv * 64 + mt * 16 + lr) * 72 + kc * 32 + kg);
#pragma unroll
            for (int nt = 0; nt < 4; ++nt)
                acc[mt][nt] = __builtin_amdgcn_mfma_f32_16x16x32_f16(af, bf[nt], acc[mt][nt], 0, 0, 0);
        }
    }

#pragma unroll
    for (int mt = 0; mt < 4; ++mt)
#pragma unroll
        for (int nt = 0; nt < 4; ++nt) {
            const int n = n0 + nt * 16 + lr;
#pragma unroll
            for (int r = 0; r < 4; ++r) {
                const int o = wv * 64 + mt * 16 + (l >> 4) * 4 + r;
                const size_t off = ((size_t)b * IC + o) * NN + n;
                outp[off] = (float)acc[mt][nt][r] + b_out[o] + x[off];
            }
        }
}

extern "C" void kernel_launch(void* const* d_in, const int* in_sizes, int n_in,
                              void* d_out, int out_size, void* d_ws, size_t ws_size,
                              hipStream_t stream)
{
    const float* x     = (const float*)d_in[0];
    const float* w_in  = (const float*)d_in[1];
    const float* b_in  = (const float*)d_in[2];
    const float* w_out = (const float*)d_in[3];
    const float* b_out = (const float*)d_in[4];
    const float* detal = (const float*)d_in[5];
    float* out = (float*)d_out;

    float* ws   = (float*)d_ws;
    float* inp  = ws + OFF_INP;
    float* s    = ws + OFF_S;
    float* pW   = ws + OFF_S;      // aliased with s (pW dead before k_co writes s)
    float* pC   = ws + OFF_PC;
    float* Tw   = ws + OFF_TW;
    float* Tc   = ws + OFF_TC;
    _Float16* wh  = (_Float16*)(ws + OFF_WT);
    _Float16* woh = (_Float16*)(ws + OFF_WOT);
    _Float16* twt = (_Float16*)(ws + OFF_TWT);
    _Float16* tct = (_Float16*)(ws + OFF_TCT);

    k_wt     <<<dim3(128),              256, 0, stream>>>(w_in, w_out, wh, woh);
    k_inconv <<<dim3(NN / 128, NB),     256, 0, stream>>>(x, wh, b_in, inp);
    k_gramW  <<<dim3(NKW, NB),          256, 0, stream>>>(inp, pW);
    k_redW   <<<dim3(64, NB),           256, 0, stream>>>(pW, Tw);
    k_softW  <<<dim3(NB, 4),           1024, 0, stream>>>(Tw, twt);
    k_gramC  <<<dim3(NKC, NB),          256, 0, stream>>>(inp, pC);
    k_redC   <<<dim3(16, NB),           256, 0, stream>>>(pC, Tc);
    k_softC  <<<dim3(NB),              1024, 0, stream>>>(Tc, tct);
    k_co     <<<dim3(NN / 128, NB),     256, 0, stream>>>(inp, tct, detal, s);
    k_wo     <<<dim3(CC, 2, NB),        256, 0, stream>>>(inp, twt, detal, s);
    k_outconv<<<dim3(NN / 64, NB),      256, 0, stream>>>(s, woh, b_out, x, out);
}